// Round 1
// baseline (639.542 us; speedup 1.0000x reference)
//
#include <hip/hip_runtime.h>

#define NN 100000

// ---------------- degree count ----------------
__global__ __launch_bounds__(256) void count_deg(const int* __restrict__ dst,
                                                 int* __restrict__ cnt, int E) {
    int e = blockIdx.x * 256 + threadIdx.x;
    if (e < E) atomicAdd(&cnt[dst[e]], 1);
}

// ---------------- single-block scan: row_ptr (exclusive), dinv_sqrt, dinv ----------------
__global__ __launch_bounds__(1024) void scan_kernel(const int* __restrict__ cnt,
                                                    int* __restrict__ row_ptr,
                                                    float* __restrict__ dinv_sqrt,
                                                    float* __restrict__ dinv, int N) {
    __shared__ int wsum[16];
    __shared__ int carry_s;
    const int tid = threadIdx.x;
    const int lane = tid & 63, wid = tid >> 6;
    if (tid == 0) carry_s = 0;
    __syncthreads();
    for (int base = 0; base < N; base += 4096) {
        int i0 = base + tid * 4;
        int v[4];
#pragma unroll
        for (int j = 0; j < 4; ++j) {
            int i = i0 + j;
            v[j] = (i < N) ? cnt[i] : 0;
        }
        int tsum = v[0] + v[1] + v[2] + v[3];
        // wave-inclusive scan of tsum
        int x = tsum;
#pragma unroll
        for (int off = 1; off < 64; off <<= 1) {
            int y = __shfl_up(x, off, 64);
            if (lane >= off) x += y;
        }
        if (lane == 63) wsum[wid] = x;
        __syncthreads();
        if (wid == 0) {
            int w = (lane < 16) ? wsum[lane] : 0;
#pragma unroll
            for (int off = 1; off < 16; off <<= 1) {
                int y = __shfl_up(w, off, 64);
                if (lane >= off) w += y;
            }
            if (lane < 16) wsum[lane] = w;
        }
        __syncthreads();
        int waveoff = (wid == 0) ? 0 : wsum[wid - 1];
        int carry = carry_s;
        int excl = carry + waveoff + (x - tsum);
#pragma unroll
        for (int j = 0; j < 4; ++j) {
            int i = i0 + j;
            if (i < N) {
                row_ptr[i] = excl;
                float deg = (float)v[j] + 1.0f;
                dinv_sqrt[i] = rsqrtf(deg);
                dinv[i] = 1.0f / deg;
            }
            excl += v[j];
        }
        __syncthreads();
        if (tid == 1023) carry_s = carry + waveoff + x;
        __syncthreads();
    }
    if (tid == 0) row_ptr[N] = carry_s;
}

// ---------------- CSR fill (+ per-edge norm) ----------------
__global__ __launch_bounds__(256) void fill_csr(const int* __restrict__ src,
                                                const int* __restrict__ dst,
                                                const int* __restrict__ row_ptr,
                                                int* __restrict__ fill,
                                                int* __restrict__ col,
                                                float* __restrict__ normv,
                                                const float* __restrict__ dinv_sqrt, int E) {
    int e = blockIdx.x * 256 + threadIdx.x;
    if (e >= E) return;
    int d = dst[e], s = src[e];
    int pos = row_ptr[d] + atomicAdd(&fill[d], 1);
    col[pos] = s;
    normv[pos] = dinv_sqrt[s] * dinv_sqrt[d];
}

// ---------------- dense GEMM h = in @ W (K=64), thread-per-row ----------------
template <int FOUT>
__global__ __launch_bounds__(256) void gemm_kernel(const float* __restrict__ in,
                                                   const float* __restrict__ W, int n,
                                                   float* __restrict__ h) {
    int row = blockIdx.x * 256 + threadIdx.x;
    if (row >= n) return;
    const float* xr = in + (size_t)row * 64;
    float r[64];
#pragma unroll
    for (int k = 0; k < 64; k += 4) {
        float4 v = *(const float4*)(xr + k);
        r[k] = v.x; r[k + 1] = v.y; r[k + 2] = v.z; r[k + 3] = v.w;
    }
    float* hr = h + (size_t)row * FOUT;
#pragma unroll 1
    for (int j0 = 0; j0 < FOUT; j0 += 16) {
        float acc[16];
#pragma unroll
        for (int jj = 0; jj < 16; ++jj) acc[jj] = 0.0f;
#pragma unroll 4
        for (int k = 0; k < 64; ++k) {
            const float* wr = W + k * FOUT + j0;  // wave-uniform -> scalar loads
#pragma unroll
            for (int jj = 0; jj < 16; ++jj) acc[jj] = fmaf(r[k], wr[jj], acc[jj]);
        }
#pragma unroll
        for (int jj = 0; jj < 16; jj += 4) {
            float4 o;
            o.x = acc[jj]; o.y = acc[jj + 1]; o.z = acc[jj + 2]; o.w = acc[jj + 3];
            *(float4*)(hr + j0 + jj) = o;
        }
    }
}

// ---------------- aggregation: out = [relu](b + h*dinv + sum_e h[src]*norm) ----------------
template <int F, bool RELU>
__global__ __launch_bounds__(256) void agg_kernel(const float* __restrict__ h,
                                                  const int* __restrict__ row_ptr,
                                                  const int* __restrict__ col,
                                                  const float* __restrict__ normv,
                                                  const float* __restrict__ dinv,
                                                  const float* __restrict__ b,
                                                  float* __restrict__ out, int n) {
    constexpr int GPB = 256 / F;  // node-groups per block
    int g = blockIdx.x * GPB + threadIdx.x / F;
    int f = threadIdx.x & (F - 1);
    if (g >= n) return;
    float acc = h[(size_t)g * F + f] * dinv[g] + b[f];
    int e0 = row_ptr[g], e1 = row_ptr[g + 1];
    for (int e = e0; e < e1; ++e) {
        int s = col[e];
        acc = fmaf(h[(size_t)s * F + f], normv[e], acc);
    }
    if (RELU) acc = fmaxf(acc, 0.0f);
    out[(size_t)g * F + f] = acc;
}

extern "C" void kernel_launch(void* const* d_in, const int* in_sizes, int n_in,
                              void* d_out, int out_size, void* d_ws, size_t ws_size,
                              hipStream_t stream) {
    const float* x  = (const float*)d_in[0];
    const int* edge = (const int*)d_in[1];
    const float* W1 = (const float*)d_in[2];
    const float* b1 = (const float*)d_in[3];
    const float* W2 = (const float*)d_in[4];
    const float* b2 = (const float*)d_in[5];
    const float* W3 = (const float*)d_in[6];
    const float* b3 = (const float*)d_in[7];
    const float* W4 = (const float*)d_in[8];
    const float* b4 = (const float*)d_in[9];

    const int N = NN;
    const int E = in_sizes[1] / 2;
    const int* src = edge;
    const int* dst = edge + E;

    char* ws = (char*)d_ws;
    size_t off = 0;
    auto alloc = [&](size_t bytes) -> void* {
        void* p = ws + off;
        off += (bytes + 255) & ~(size_t)255;
        return p;
    };
    int* cnt       = (int*)alloc((size_t)2 * N * sizeof(int));  // cnt + fill contiguous
    int* fill      = cnt + N;
    int* row_ptr   = (int*)alloc((size_t)(N + 1) * sizeof(int));
    int* col       = (int*)alloc((size_t)E * sizeof(int));
    float* normv   = (float*)alloc((size_t)E * sizeof(float));
    float* dis     = (float*)alloc((size_t)N * sizeof(float));
    float* dinv    = (float*)alloc((size_t)N * sizeof(float));
    float* bufA    = (float*)alloc((size_t)N * 64 * sizeof(float));
    float* bufB    = (float*)alloc((size_t)N * 64 * sizeof(float));

    hipMemsetAsync(cnt, 0, (size_t)2 * N * sizeof(int), stream);
    count_deg<<<(E + 255) / 256, 256, 0, stream>>>(dst, cnt, E);
    scan_kernel<<<1, 1024, 0, stream>>>(cnt, row_ptr, dis, dinv, N);
    fill_csr<<<(E + 255) / 256, 256, 0, stream>>>(src, dst, row_ptr, fill, col, normv, dis, E);

    const int gemm_grid = (N + 255) / 256;
    // layer 1
    gemm_kernel<64><<<gemm_grid, 256, 0, stream>>>(x, W1, N, bufB);
    agg_kernel<64, true><<<(N + 3) / 4, 256, 0, stream>>>(bufB, row_ptr, col, normv, dinv, b1, bufA, N);
    // layer 2
    gemm_kernel<64><<<gemm_grid, 256, 0, stream>>>(bufA, W2, N, bufB);
    agg_kernel<64, true><<<(N + 3) / 4, 256, 0, stream>>>(bufB, row_ptr, col, normv, dinv, b2, bufA, N);
    // layer 3
    gemm_kernel<64><<<gemm_grid, 256, 0, stream>>>(bufA, W3, N, bufB);
    agg_kernel<64, true><<<(N + 3) / 4, 256, 0, stream>>>(bufB, row_ptr, col, normv, dinv, b3, bufA, N);
    // layer 4 (FOUT=32, no relu, straight to d_out)
    gemm_kernel<32><<<gemm_grid, 256, 0, stream>>>(bufA, W4, N, bufB);
    agg_kernel<32, false><<<(N + 7) / 8, 256, 0, stream>>>(bufB, row_ptr, col, normv, dinv, b4, (float*)d_out, N);
}

// Round 2
// 544.399 us; speedup vs baseline: 1.1748x; 1.1748x over previous
//
#include <hip/hip_runtime.h>

#define NN 100000
#define SCAN_CHUNK 1024

// ---------------- degree count ----------------
__global__ __launch_bounds__(256) void count_deg(const int* __restrict__ dst,
                                                 int* __restrict__ cnt, int E) {
    int e = blockIdx.x * 256 + threadIdx.x;
    if (e < E) atomicAdd(&cnt[dst[e]], 1);
}

// ---------------- pass 1: per-block (1024-elem chunk) sums ----------------
__global__ __launch_bounds__(256) void block_sum(const int* __restrict__ cnt,
                                                 int* __restrict__ bsum, int N) {
    __shared__ int ws[4];
    const int tid = threadIdx.x, lane = tid & 63, wid = tid >> 6;
    int i0 = blockIdx.x * SCAN_CHUNK + tid * 4;
    int s = 0;
    if (i0 + 3 < N) {
        int4 v = *(const int4*)(cnt + i0);
        s = v.x + v.y + v.z + v.w;
    } else {
#pragma unroll
        for (int j = 0; j < 4; ++j) { int i = i0 + j; if (i < N) s += cnt[i]; }
    }
#pragma unroll
    for (int off = 32; off; off >>= 1) s += __shfl_down(s, off, 64);
    if (lane == 0) ws[wid] = s;
    __syncthreads();
    if (tid == 0) bsum[blockIdx.x] = ws[0] + ws[1] + ws[2] + ws[3];
}

// ---------------- pass 2: scan the block sums (nb <= 256), write total ----------------
__global__ __launch_bounds__(256) void scan_bsums(int* __restrict__ bsum, int nb,
                                                  int* __restrict__ row_ptr, int N) {
    __shared__ int ws[4];
    const int tid = threadIdx.x, lane = tid & 63, wid = tid >> 6;
    int v = (tid < nb) ? bsum[tid] : 0;
    int x = v;
#pragma unroll
    for (int off = 1; off < 64; off <<= 1) {
        int y = __shfl_up(x, off, 64);
        if (lane >= off) x += y;
    }
    if (lane == 63) ws[wid] = x;
    __syncthreads();
    int woff = 0;
    for (int w = 0; w < wid; ++w) woff += ws[w];
    int incl = x + woff;
    if (tid < nb) bsum[tid] = incl - v;        // exclusive block offset
    if (tid == nb - 1) row_ptr[N] = incl;      // grand total = E
}

// ---------------- pass 3: local exclusive scan + block offset + deg terms ----------------
__global__ __launch_bounds__(256) void scan_final(const int* __restrict__ cnt,
                                                  const int* __restrict__ bsum,
                                                  int* __restrict__ row_ptr,
                                                  float* __restrict__ dinv_sqrt,
                                                  float* __restrict__ dinv, int N) {
    __shared__ int ws[4];
    const int tid = threadIdx.x, lane = tid & 63, wid = tid >> 6;
    int i0 = blockIdx.x * SCAN_CHUNK + tid * 4;
    int v[4];
    if (i0 + 3 < N) {
        int4 t = *(const int4*)(cnt + i0);
        v[0] = t.x; v[1] = t.y; v[2] = t.z; v[3] = t.w;
    } else {
#pragma unroll
        for (int j = 0; j < 4; ++j) { int i = i0 + j; v[j] = (i < N) ? cnt[i] : 0; }
    }
    int tsum = v[0] + v[1] + v[2] + v[3];
    int x = tsum;
#pragma unroll
    for (int off = 1; off < 64; off <<= 1) {
        int y = __shfl_up(x, off, 64);
        if (lane >= off) x += y;
    }
    if (lane == 63) ws[wid] = x;
    __syncthreads();
    int woff = 0;
    for (int w = 0; w < wid; ++w) woff += ws[w];
    int excl = bsum[blockIdx.x] + woff + (x - tsum);
#pragma unroll
    for (int j = 0; j < 4; ++j) {
        int i = i0 + j;
        if (i < N) {
            row_ptr[i] = excl;
            float deg = (float)v[j] + 1.0f;
            dinv_sqrt[i] = rsqrtf(deg);
            dinv[i] = 1.0f / deg;
        }
        excl += v[j];
    }
}

// ---------------- CSR fill (+ per-edge norm) ----------------
__global__ __launch_bounds__(256) void fill_csr(const int* __restrict__ src,
                                                const int* __restrict__ dst,
                                                const int* __restrict__ row_ptr,
                                                int* __restrict__ fill,
                                                int* __restrict__ col,
                                                float* __restrict__ normv,
                                                const float* __restrict__ dinv_sqrt, int E) {
    int e = blockIdx.x * 256 + threadIdx.x;
    if (e >= E) return;
    int d = dst[e], s = src[e];
    int pos = row_ptr[d] + atomicAdd(&fill[d], 1);
    col[pos] = s;
    normv[pos] = dinv_sqrt[s] * dinv_sqrt[d];
}

// ---------------- dense GEMM h = in @ W (K=64), thread-per-row ----------------
template <int FOUT>
__global__ __launch_bounds__(256) void gemm_kernel(const float* __restrict__ in,
                                                   const float* __restrict__ W, int n,
                                                   float* __restrict__ h) {
    int row = blockIdx.x * 256 + threadIdx.x;
    if (row >= n) return;
    const float* xr = in + (size_t)row * 64;
    float r[64];
#pragma unroll
    for (int k = 0; k < 64; k += 4) {
        float4 v = *(const float4*)(xr + k);
        r[k] = v.x; r[k + 1] = v.y; r[k + 2] = v.z; r[k + 3] = v.w;
    }
    float* hr = h + (size_t)row * FOUT;
#pragma unroll 1
    for (int j0 = 0; j0 < FOUT; j0 += 16) {
        float acc[16];
#pragma unroll
        for (int jj = 0; jj < 16; ++jj) acc[jj] = 0.0f;
#pragma unroll 4
        for (int k = 0; k < 64; ++k) {
            const float* wr = W + k * FOUT + j0;  // wave-uniform -> scalar loads
#pragma unroll
            for (int jj = 0; jj < 16; ++jj) acc[jj] = fmaf(r[k], wr[jj], acc[jj]);
        }
#pragma unroll
        for (int jj = 0; jj < 16; jj += 4) {
            float4 o;
            o.x = acc[jj]; o.y = acc[jj + 1]; o.z = acc[jj + 2]; o.w = acc[jj + 3];
            *(float4*)(hr + j0 + jj) = o;
        }
    }
}

// ---------------- aggregation: out = [relu](b + h*dinv + sum_e h[src]*norm) ----------------
template <int F, bool RELU>
__global__ __launch_bounds__(256) void agg_kernel(const float* __restrict__ h,
                                                  const int* __restrict__ row_ptr,
                                                  const int* __restrict__ col,
                                                  const float* __restrict__ normv,
                                                  const float* __restrict__ dinv,
                                                  const float* __restrict__ b,
                                                  float* __restrict__ out, int n) {
    constexpr int GPB = 256 / F;  // node-groups per block
    int g = blockIdx.x * GPB + threadIdx.x / F;
    int f = threadIdx.x & (F - 1);
    if (g >= n) return;
    float acc = h[(size_t)g * F + f] * dinv[g] + b[f];
    int e0 = row_ptr[g], e1 = row_ptr[g + 1];
    for (int e = e0; e < e1; ++e) {
        int s = col[e];
        acc = fmaf(h[(size_t)s * F + f], normv[e], acc);
    }
    if (RELU) acc = fmaxf(acc, 0.0f);
    out[(size_t)g * F + f] = acc;
}

extern "C" void kernel_launch(void* const* d_in, const int* in_sizes, int n_in,
                              void* d_out, int out_size, void* d_ws, size_t ws_size,
                              hipStream_t stream) {
    const float* x  = (const float*)d_in[0];
    const int* edge = (const int*)d_in[1];
    const float* b1 = (const float*)d_in[3];
    const float* b2 = (const float*)d_in[5];
    const float* b3 = (const float*)d_in[7];
    const float* b4 = (const float*)d_in[9];
    const float* W1 = (const float*)d_in[2];
    const float* W2 = (const float*)d_in[4];
    const float* W3 = (const float*)d_in[6];
    const float* W4 = (const float*)d_in[8];

    const int N = NN;
    const int E = in_sizes[1] / 2;
    const int* src = edge;
    const int* dst = edge + E;

    char* ws = (char*)d_ws;
    size_t off = 0;
    auto alloc = [&](size_t bytes) -> void* {
        void* p = ws + off;
        off += (bytes + 255) & ~(size_t)255;
        return p;
    };
    int* cnt       = (int*)alloc((size_t)2 * N * sizeof(int));  // cnt + fill contiguous
    int* fill      = cnt + N;
    int* row_ptr   = (int*)alloc((size_t)(N + 1) * sizeof(int));
    int* col       = (int*)alloc((size_t)E * sizeof(int));
    float* normv   = (float*)alloc((size_t)E * sizeof(float));
    float* dis     = (float*)alloc((size_t)N * sizeof(float));
    float* dinv    = (float*)alloc((size_t)N * sizeof(float));
    int* bsum      = (int*)alloc((size_t)256 * sizeof(int));
    float* bufA    = (float*)alloc((size_t)N * 64 * sizeof(float));
    float* bufB    = (float*)alloc((size_t)N * 64 * sizeof(float));

    const int nb = (N + SCAN_CHUNK - 1) / SCAN_CHUNK;  // 98

    hipMemsetAsync(cnt, 0, (size_t)2 * N * sizeof(int), stream);
    count_deg<<<(E + 255) / 256, 256, 0, stream>>>(dst, cnt, E);
    block_sum<<<nb, 256, 0, stream>>>(cnt, bsum, N);
    scan_bsums<<<1, 256, 0, stream>>>(bsum, nb, row_ptr, N);
    scan_final<<<nb, 256, 0, stream>>>(cnt, bsum, row_ptr, dis, dinv, N);
    fill_csr<<<(E + 255) / 256, 256, 0, stream>>>(src, dst, row_ptr, fill, col, normv, dis, E);

    const int gemm_grid = (N + 255) / 256;
    // layer 1
    gemm_kernel<64><<<gemm_grid, 256, 0, stream>>>(x, W1, N, bufB);
    agg_kernel<64, true><<<(N + 3) / 4, 256, 0, stream>>>(bufB, row_ptr, col, normv, dinv, b1, bufA, N);
    // layer 2
    gemm_kernel<64><<<gemm_grid, 256, 0, stream>>>(bufA, W2, N, bufB);
    agg_kernel<64, true><<<(N + 3) / 4, 256, 0, stream>>>(bufB, row_ptr, col, normv, dinv, b2, bufA, N);
    // layer 3
    gemm_kernel<64><<<gemm_grid, 256, 0, stream>>>(bufA, W3, N, bufB);
    agg_kernel<64, true><<<(N + 3) / 4, 256, 0, stream>>>(bufB, row_ptr, col, normv, dinv, b3, bufA, N);
    // layer 4 (FOUT=32, no relu, straight to d_out)
    gemm_kernel<32><<<gemm_grid, 256, 0, stream>>>(bufA, W4, N, bufB);
    agg_kernel<32, false><<<(N + 7) / 8, 256, 0, stream>>>(bufB, row_ptr, col, normv, dinv, b4, (float*)d_out, N);
}

// Round 3
// 409.989 us; speedup vs baseline: 1.5599x; 1.3278x over previous
//
#include <hip/hip_runtime.h>

#define NN 100000
#define SCAN_CHUNK 1024

// ---------------- degree count ----------------
__global__ __launch_bounds__(256) void count_deg(const int* __restrict__ dst,
                                                 int* __restrict__ cnt, int E) {
    int e = blockIdx.x * 256 + threadIdx.x;
    if (e < E) atomicAdd(&cnt[dst[e]], 1);
}

// ---------------- pass 1: per-block (1024-elem chunk) sums ----------------
__global__ __launch_bounds__(256) void block_sum(const int* __restrict__ cnt,
                                                 int* __restrict__ bsum, int N) {
    __shared__ int ws[4];
    const int tid = threadIdx.x, lane = tid & 63, wid = tid >> 6;
    int i0 = blockIdx.x * SCAN_CHUNK + tid * 4;
    int s = 0;
    if (i0 + 3 < N) {
        int4 v = *(const int4*)(cnt + i0);
        s = v.x + v.y + v.z + v.w;
    } else {
#pragma unroll
        for (int j = 0; j < 4; ++j) { int i = i0 + j; if (i < N) s += cnt[i]; }
    }
#pragma unroll
    for (int off = 32; off; off >>= 1) s += __shfl_down(s, off, 64);
    if (lane == 0) ws[wid] = s;
    __syncthreads();
    if (tid == 0) bsum[blockIdx.x] = ws[0] + ws[1] + ws[2] + ws[3];
}

// ---------------- pass 2: scan the block sums (nb <= 256), write total ----------------
__global__ __launch_bounds__(256) void scan_bsums(int* __restrict__ bsum, int nb,
                                                  int* __restrict__ row_ptr, int N) {
    __shared__ int ws[4];
    const int tid = threadIdx.x, lane = tid & 63, wid = tid >> 6;
    int v = (tid < nb) ? bsum[tid] : 0;
    int x = v;
#pragma unroll
    for (int off = 1; off < 64; off <<= 1) {
        int y = __shfl_up(x, off, 64);
        if (lane >= off) x += y;
    }
    if (lane == 63) ws[wid] = x;
    __syncthreads();
    int woff = 0;
    for (int w = 0; w < wid; ++w) woff += ws[w];
    int incl = x + woff;
    if (tid < nb) bsum[tid] = incl - v;        // exclusive block offset
    if (tid == nb - 1) row_ptr[N] = incl;      // grand total = E
}

// ---------------- pass 3: local exclusive scan + block offset + deg terms ----------------
__global__ __launch_bounds__(256) void scan_final(const int* __restrict__ cnt,
                                                  const int* __restrict__ bsum,
                                                  int* __restrict__ row_ptr,
                                                  float* __restrict__ dinv_sqrt,
                                                  float* __restrict__ dinv, int N) {
    __shared__ int ws[4];
    const int tid = threadIdx.x, lane = tid & 63, wid = tid >> 6;
    int i0 = blockIdx.x * SCAN_CHUNK + tid * 4;
    int v[4];
    if (i0 + 3 < N) {
        int4 t = *(const int4*)(cnt + i0);
        v[0] = t.x; v[1] = t.y; v[2] = t.z; v[3] = t.w;
    } else {
#pragma unroll
        for (int j = 0; j < 4; ++j) { int i = i0 + j; v[j] = (i < N) ? cnt[i] : 0; }
    }
    int tsum = v[0] + v[1] + v[2] + v[3];
    int x = tsum;
#pragma unroll
    for (int off = 1; off < 64; off <<= 1) {
        int y = __shfl_up(x, off, 64);
        if (lane >= off) x += y;
    }
    if (lane == 63) ws[wid] = x;
    __syncthreads();
    int woff = 0;
    for (int w = 0; w < wid; ++w) woff += ws[w];
    int excl = bsum[blockIdx.x] + woff + (x - tsum);
#pragma unroll
    for (int j = 0; j < 4; ++j) {
        int i = i0 + j;
        if (i < N) {
            row_ptr[i] = excl;
            float deg = (float)v[j] + 1.0f;
            dinv_sqrt[i] = rsqrtf(deg);
            dinv[i] = 1.0f / deg;
        }
        excl += v[j];
    }
}

// ---------------- CSR fill (+ per-edge norm) ----------------
__global__ __launch_bounds__(256) void fill_csr(const int* __restrict__ src,
                                                const int* __restrict__ dst,
                                                const int* __restrict__ row_ptr,
                                                int* __restrict__ fill,
                                                int* __restrict__ col,
                                                float* __restrict__ normv,
                                                const float* __restrict__ dinv_sqrt, int E) {
    int e = blockIdx.x * 256 + threadIdx.x;
    if (e >= E) return;
    int d = dst[e], s = src[e];
    int pos = row_ptr[d] + atomicAdd(&fill[d], 1);
    col[pos] = s;
    normv[pos] = dinv_sqrt[s] * dinv_sqrt[d];
}

// ---------------- dense GEMM h = in @ W (K=64), thread-per-row ----------------
template <int FOUT>
__global__ __launch_bounds__(256) void gemm_kernel(const float* __restrict__ in,
                                                   const float* __restrict__ W, int n,
                                                   float* __restrict__ h) {
    int row = blockIdx.x * 256 + threadIdx.x;
    if (row >= n) return;
    const float* xr = in + (size_t)row * 64;
    float r[64];
#pragma unroll
    for (int k = 0; k < 64; k += 4) {
        float4 v = *(const float4*)(xr + k);
        r[k] = v.x; r[k + 1] = v.y; r[k + 2] = v.z; r[k + 3] = v.w;
    }
    float* hr = h + (size_t)row * FOUT;
#pragma unroll 1
    for (int j0 = 0; j0 < FOUT; j0 += 16) {
        float acc[16];
#pragma unroll
        for (int jj = 0; jj < 16; ++jj) acc[jj] = 0.0f;
#pragma unroll 4
        for (int k = 0; k < 64; ++k) {
            const float* wr = W + k * FOUT + j0;  // wave-uniform -> scalar loads
#pragma unroll
            for (int jj = 0; jj < 16; ++jj) acc[jj] = fmaf(r[k], wr[jj], acc[jj]);
        }
#pragma unroll
        for (int jj = 0; jj < 16; jj += 4) {
            float4 o;
            o.x = acc[jj]; o.y = acc[jj + 1]; o.z = acc[jj + 2]; o.w = acc[jj + 3];
            *(float4*)(hr + j0 + jj) = o;
        }
    }
}

// ---------------- aggregation: out = [relu](b + h*dinv + sum_e h[src]*norm) ----------------
// 4x edge unroll: 4 independent gathers in flight per wave (latency hiding)
template <int F, bool RELU>
__global__ __launch_bounds__(256) void agg_kernel(const float* __restrict__ h,
                                                  const int* __restrict__ row_ptr,
                                                  const int* __restrict__ col,
                                                  const float* __restrict__ normv,
                                                  const float* __restrict__ dinv,
                                                  const float* __restrict__ b,
                                                  float* __restrict__ out, int n) {
    constexpr int GPB = 256 / F;  // node-groups per block
    int g = blockIdx.x * GPB + threadIdx.x / F;
    int f = threadIdx.x & (F - 1);
    if (g >= n) return;
    float acc = h[(size_t)g * F + f] * dinv[g] + b[f];
    float acc2 = 0.0f;
    int e0 = row_ptr[g], e1 = row_ptr[g + 1];
    int e = e0;
    for (; e + 4 <= e1; e += 4) {
        int s0 = col[e + 0], s1 = col[e + 1], s2 = col[e + 2], s3 = col[e + 3];
        float n0 = normv[e + 0], n1 = normv[e + 1], n2 = normv[e + 2], n3 = normv[e + 3];
        float v0 = h[(size_t)s0 * F + f];
        float v1 = h[(size_t)s1 * F + f];
        float v2 = h[(size_t)s2 * F + f];
        float v3 = h[(size_t)s3 * F + f];
        acc  = fmaf(v0, n0, acc);
        acc2 = fmaf(v1, n1, acc2);
        acc  = fmaf(v2, n2, acc);
        acc2 = fmaf(v3, n3, acc2);
    }
    if (e + 2 <= e1) {
        int s0 = col[e + 0], s1 = col[e + 1];
        float n0 = normv[e + 0], n1 = normv[e + 1];
        float v0 = h[(size_t)s0 * F + f];
        float v1 = h[(size_t)s1 * F + f];
        acc  = fmaf(v0, n0, acc);
        acc2 = fmaf(v1, n1, acc2);
        e += 2;
    }
    if (e < e1) {
        acc = fmaf(h[(size_t)col[e] * F + f], normv[e], acc);
    }
    acc += acc2;
    if (RELU) acc = fmaxf(acc, 0.0f);
    out[(size_t)g * F + f] = acc;
}

extern "C" void kernel_launch(void* const* d_in, const int* in_sizes, int n_in,
                              void* d_out, int out_size, void* d_ws, size_t ws_size,
                              hipStream_t stream) {
    const float* x  = (const float*)d_in[0];
    const int* edge = (const int*)d_in[1];
    const float* W1 = (const float*)d_in[2];
    const float* b1 = (const float*)d_in[3];
    const float* W2 = (const float*)d_in[4];
    const float* b2 = (const float*)d_in[5];
    const float* W3 = (const float*)d_in[6];
    const float* b3 = (const float*)d_in[7];
    const float* W4 = (const float*)d_in[8];
    const float* b4 = (const float*)d_in[9];

    const int N = NN;
    const int E = in_sizes[1] / 2;
    const int* src = edge;
    const int* dst = edge + E;

    char* ws = (char*)d_ws;
    size_t off = 0;
    auto alloc = [&](size_t bytes) -> void* {
        void* p = ws + off;
        off += (bytes + 255) & ~(size_t)255;
        return p;
    };
    int* cnt       = (int*)alloc((size_t)2 * N * sizeof(int));  // cnt + fill contiguous
    int* fill      = cnt + N;
    int* row_ptr   = (int*)alloc((size_t)(N + 1) * sizeof(int));
    int* col       = (int*)alloc((size_t)E * sizeof(int));
    float* normv   = (float*)alloc((size_t)E * sizeof(float));
    float* dis     = (float*)alloc((size_t)N * sizeof(float));
    float* dinv    = (float*)alloc((size_t)N * sizeof(float));
    int* bsum      = (int*)alloc((size_t)256 * sizeof(int));
    float* bufA    = (float*)alloc((size_t)N * 64 * sizeof(float));
    float* bufB    = (float*)alloc((size_t)N * 64 * sizeof(float));

    const int nb = (N + SCAN_CHUNK - 1) / SCAN_CHUNK;  // 98

    hipMemsetAsync(cnt, 0, (size_t)2 * N * sizeof(int), stream);
    count_deg<<<(E + 255) / 256, 256, 0, stream>>>(dst, cnt, E);
    block_sum<<<nb, 256, 0, stream>>>(cnt, bsum, N);
    scan_bsums<<<1, 256, 0, stream>>>(bsum, nb, row_ptr, N);
    scan_final<<<nb, 256, 0, stream>>>(cnt, bsum, row_ptr, dis, dinv, N);
    fill_csr<<<(E + 255) / 256, 256, 0, stream>>>(src, dst, row_ptr, fill, col, normv, dis, E);

    const int gemm_grid = (N + 255) / 256;
    // layer 1
    gemm_kernel<64><<<gemm_grid, 256, 0, stream>>>(x, W1, N, bufB);
    agg_kernel<64, true><<<(N + 3) / 4, 256, 0, stream>>>(bufB, row_ptr, col, normv, dinv, b1, bufA, N);
    // layer 2
    gemm_kernel<64><<<gemm_grid, 256, 0, stream>>>(bufA, W2, N, bufB);
    agg_kernel<64, true><<<(N + 3) / 4, 256, 0, stream>>>(bufB, row_ptr, col, normv, dinv, b2, bufA, N);
    // layer 3
    gemm_kernel<64><<<gemm_grid, 256, 0, stream>>>(bufA, W3, N, bufB);
    agg_kernel<64, true><<<(N + 3) / 4, 256, 0, stream>>>(bufB, row_ptr, col, normv, dinv, b3, bufA, N);
    // layer 4 (FOUT=32, no relu, straight to d_out)
    gemm_kernel<32><<<gemm_grid, 256, 0, stream>>>(bufA, W4, N, bufB);
    agg_kernel<32, false><<<(N + 7) / 8, 256, 0, stream>>>(bufB, row_ptr, col, normv, dinv, b4, (float*)d_out, N);
}

// Round 4
// 332.621 us; speedup vs baseline: 1.9227x; 1.2326x over previous
//
#include <hip/hip_runtime.h>

#define NN 100000
#define SCAN_CHUNK 1024

// ---------------- degree count ----------------
__global__ __launch_bounds__(256) void count_deg(const int* __restrict__ dst,
                                                 int* __restrict__ cnt, int E) {
    int e = blockIdx.x * 256 + threadIdx.x;
    if (e < E) atomicAdd(&cnt[dst[e]], 1);
}

// ---------------- pass 1: per-block (1024-elem chunk) sums ----------------
__global__ __launch_bounds__(256) void block_sum(const int* __restrict__ cnt,
                                                 int* __restrict__ bsum, int N) {
    __shared__ int ws[4];
    const int tid = threadIdx.x, lane = tid & 63, wid = tid >> 6;
    int i0 = blockIdx.x * SCAN_CHUNK + tid * 4;
    int s = 0;
    if (i0 + 3 < N) {
        int4 v = *(const int4*)(cnt + i0);
        s = v.x + v.y + v.z + v.w;
    } else {
#pragma unroll
        for (int j = 0; j < 4; ++j) { int i = i0 + j; if (i < N) s += cnt[i]; }
    }
#pragma unroll
    for (int off = 32; off; off >>= 1) s += __shfl_down(s, off, 64);
    if (lane == 0) ws[wid] = s;
    __syncthreads();
    if (tid == 0) bsum[blockIdx.x] = ws[0] + ws[1] + ws[2] + ws[3];
}

// ---------------- pass 2: scan the block sums (nb <= 256), write total ----------------
__global__ __launch_bounds__(256) void scan_bsums(int* __restrict__ bsum, int nb,
                                                  int* __restrict__ row_ptr, int N) {
    __shared__ int ws[4];
    const int tid = threadIdx.x, lane = tid & 63, wid = tid >> 6;
    int v = (tid < nb) ? bsum[tid] : 0;
    int x = v;
#pragma unroll
    for (int off = 1; off < 64; off <<= 1) {
        int y = __shfl_up(x, off, 64);
        if (lane >= off) x += y;
    }
    if (lane == 63) ws[wid] = x;
    __syncthreads();
    int woff = 0;
    for (int w = 0; w < wid; ++w) woff += ws[w];
    int incl = x + woff;
    if (tid < nb) bsum[tid] = incl - v;        // exclusive block offset
    if (tid == nb - 1) row_ptr[N] = incl;      // grand total = E
}

// ---------------- pass 3: local exclusive scan + block offset + deg terms ----------------
__global__ __launch_bounds__(256) void scan_final(const int* __restrict__ cnt,
                                                  const int* __restrict__ bsum,
                                                  int* __restrict__ row_ptr,
                                                  float* __restrict__ dinv_sqrt,
                                                  float* __restrict__ dinv, int N) {
    __shared__ int ws[4];
    const int tid = threadIdx.x, lane = tid & 63, wid = tid >> 6;
    int i0 = blockIdx.x * SCAN_CHUNK + tid * 4;
    int v[4];
    if (i0 + 3 < N) {
        int4 t = *(const int4*)(cnt + i0);
        v[0] = t.x; v[1] = t.y; v[2] = t.z; v[3] = t.w;
    } else {
#pragma unroll
        for (int j = 0; j < 4; ++j) { int i = i0 + j; v[j] = (i < N) ? cnt[i] : 0; }
    }
    int tsum = v[0] + v[1] + v[2] + v[3];
    int x = tsum;
#pragma unroll
    for (int off = 1; off < 64; off <<= 1) {
        int y = __shfl_up(x, off, 64);
        if (lane >= off) x += y;
    }
    if (lane == 63) ws[wid] = x;
    __syncthreads();
    int woff = 0;
    for (int w = 0; w < wid; ++w) woff += ws[w];
    int excl = bsum[blockIdx.x] + woff + (x - tsum);
#pragma unroll
    for (int j = 0; j < 4; ++j) {
        int i = i0 + j;
        if (i < N) {
            row_ptr[i] = excl;
            float deg = (float)v[j] + 1.0f;
            dinv_sqrt[i] = rsqrtf(deg);
            dinv[i] = 1.0f / deg;
        }
        excl += v[j];
    }
}

// ---------------- CSR fill: interleaved (col, norm) int2 — one 8B scattered write ----------------
__global__ __launch_bounds__(256) void fill_csr(const int* __restrict__ src,
                                                const int* __restrict__ dst,
                                                const int* __restrict__ row_ptr,
                                                int* __restrict__ fill,
                                                int2* __restrict__ ecol,
                                                const float* __restrict__ dinv_sqrt, int E) {
    int e = blockIdx.x * 256 + threadIdx.x;
    if (e >= E) return;
    int d = dst[e], s = src[e];
    int pos = row_ptr[d] + atomicAdd(&fill[d], 1);
    int2 v;
    v.x = s;
    v.y = __float_as_int(dinv_sqrt[s] * dinv_sqrt[d]);
    ecol[pos] = v;
}

// ---------------- dense GEMM h = in @ W (K=64), LDS-tiled ----------------
// R*FOUT == 1024: each of 256 threads computes one float4 of output.
template <int FOUT, int R>
__global__ __launch_bounds__(256) void gemm_lds(const float* __restrict__ in,
                                                const float* __restrict__ W, int n,
                                                float* __restrict__ h) {
    constexpr int XS = 68;  // padded x row stride (floats): 4-row bank spread, 16B aligned
    __shared__ float xs[R * XS];
    __shared__ float ws[64 * FOUT];
    const int tid = threadIdx.x;
    const int r0 = blockIdx.x * R;
    // stage x tile (R x 64), coalesced float4
    {
        const float4* xsrc = (const float4*)(in + (size_t)r0 * 64);
        constexpr int NF4 = R * 16;
#pragma unroll
        for (int i = tid; i < NF4; i += 256) {
            int row = i >> 4, kk = (i & 15) << 2;
            float4 v = make_float4(0.f, 0.f, 0.f, 0.f);
            if (r0 + row < n) v = xsrc[i];
            *(float4*)(xs + row * XS + kk) = v;
        }
        // stage W (64 x FOUT), coalesced float4
        const float4* wsrc = (const float4*)W;
#pragma unroll
        for (int i = tid; i < 64 * FOUT / 4; i += 256)
            *(float4*)(ws + i * 4) = wsrc[i];
    }
    __syncthreads();
    constexpr int CG = FOUT / 4;  // col groups per row
    const int row = tid / CG;
    const int col = (tid % CG) * 4;
    float4 acc = make_float4(0.f, 0.f, 0.f, 0.f);
#pragma unroll
    for (int k = 0; k < 64; k += 4) {
        float4 xv = *(const float4*)(xs + row * XS + k);
#pragma unroll
        for (int kk = 0; kk < 4; ++kk) {
            float a = (&xv.x)[kk];
            float4 wv = *(const float4*)(ws + (k + kk) * FOUT + col);
            acc.x = fmaf(a, wv.x, acc.x);
            acc.y = fmaf(a, wv.y, acc.y);
            acc.z = fmaf(a, wv.z, acc.z);
            acc.w = fmaf(a, wv.w, acc.w);
        }
    }
    int orow = r0 + row;
    if (orow < n) *(float4*)(h + (size_t)orow * FOUT + col) = acc;
}

// ---------------- aggregation: out = [relu](b + h*dinv + sum_e h[src]*norm) ----------------
// 4x edge unroll: 4 independent gathers in flight per wave (latency hiding)
template <int F, bool RELU>
__global__ __launch_bounds__(256) void agg_kernel(const float* __restrict__ h,
                                                  const int* __restrict__ row_ptr,
                                                  const int2* __restrict__ ecol,
                                                  const float* __restrict__ dinv,
                                                  const float* __restrict__ b,
                                                  float* __restrict__ out, int n) {
    constexpr int GPB = 256 / F;  // node-groups per block
    int g = blockIdx.x * GPB + threadIdx.x / F;
    int f = threadIdx.x & (F - 1);
    if (g >= n) return;
    float acc = h[(size_t)g * F + f] * dinv[g] + b[f];
    float acc2 = 0.0f;
    int e0 = row_ptr[g], e1 = row_ptr[g + 1];
    int e = e0;
    for (; e + 4 <= e1; e += 4) {
        int2 c0 = ecol[e + 0], c1 = ecol[e + 1], c2 = ecol[e + 2], c3 = ecol[e + 3];
        float v0 = h[(size_t)c0.x * F + f];
        float v1 = h[(size_t)c1.x * F + f];
        float v2 = h[(size_t)c2.x * F + f];
        float v3 = h[(size_t)c3.x * F + f];
        acc  = fmaf(v0, __int_as_float(c0.y), acc);
        acc2 = fmaf(v1, __int_as_float(c1.y), acc2);
        acc  = fmaf(v2, __int_as_float(c2.y), acc);
        acc2 = fmaf(v3, __int_as_float(c3.y), acc2);
    }
    if (e + 2 <= e1) {
        int2 c0 = ecol[e + 0], c1 = ecol[e + 1];
        float v0 = h[(size_t)c0.x * F + f];
        float v1 = h[(size_t)c1.x * F + f];
        acc  = fmaf(v0, __int_as_float(c0.y), acc);
        acc2 = fmaf(v1, __int_as_float(c1.y), acc2);
        e += 2;
    }
    if (e < e1) {
        int2 c0 = ecol[e];
        acc = fmaf(h[(size_t)c0.x * F + f], __int_as_float(c0.y), acc);
    }
    acc += acc2;
    if (RELU) acc = fmaxf(acc, 0.0f);
    out[(size_t)g * F + f] = acc;
}

extern "C" void kernel_launch(void* const* d_in, const int* in_sizes, int n_in,
                              void* d_out, int out_size, void* d_ws, size_t ws_size,
                              hipStream_t stream) {
    const float* x  = (const float*)d_in[0];
    const int* edge = (const int*)d_in[1];
    const float* W1 = (const float*)d_in[2];
    const float* b1 = (const float*)d_in[3];
    const float* W2 = (const float*)d_in[4];
    const float* b2 = (const float*)d_in[5];
    const float* W3 = (const float*)d_in[6];
    const float* b3 = (const float*)d_in[7];
    const float* W4 = (const float*)d_in[8];
    const float* b4 = (const float*)d_in[9];

    const int N = NN;
    const int E = in_sizes[1] / 2;
    const int* src = edge;
    const int* dst = edge + E;

    char* ws = (char*)d_ws;
    size_t off = 0;
    auto alloc = [&](size_t bytes) -> void* {
        void* p = ws + off;
        off += (bytes + 255) & ~(size_t)255;
        return p;
    };
    int* cnt       = (int*)alloc((size_t)2 * N * sizeof(int));  // cnt + fill contiguous
    int* fill      = cnt + N;
    int* row_ptr   = (int*)alloc((size_t)(N + 1) * sizeof(int));
    int2* ecol     = (int2*)alloc((size_t)E * sizeof(int2));
    float* dis     = (float*)alloc((size_t)N * sizeof(float));
    float* dinv    = (float*)alloc((size_t)N * sizeof(float));
    int* bsum      = (int*)alloc((size_t)256 * sizeof(int));
    float* bufA    = (float*)alloc((size_t)N * 64 * sizeof(float));
    float* bufB    = (float*)alloc((size_t)N * 64 * sizeof(float));

    const int nb = (N + SCAN_CHUNK - 1) / SCAN_CHUNK;  // 98

    hipMemsetAsync(cnt, 0, (size_t)2 * N * sizeof(int), stream);
    count_deg<<<(E + 255) / 256, 256, 0, stream>>>(dst, cnt, E);
    block_sum<<<nb, 256, 0, stream>>>(cnt, bsum, N);
    scan_bsums<<<1, 256, 0, stream>>>(bsum, nb, row_ptr, N);
    scan_final<<<nb, 256, 0, stream>>>(cnt, bsum, row_ptr, dis, dinv, N);
    fill_csr<<<(E + 255) / 256, 256, 0, stream>>>(src, dst, row_ptr, fill, ecol, dis, E);

    // layer 1
    gemm_lds<64, 16><<<(N + 15) / 16, 256, 0, stream>>>(x, W1, N, bufB);
    agg_kernel<64, true><<<(N + 3) / 4, 256, 0, stream>>>(bufB, row_ptr, ecol, dinv, b1, bufA, N);
    // layer 2
    gemm_lds<64, 16><<<(N + 15) / 16, 256, 0, stream>>>(bufA, W2, N, bufB);
    agg_kernel<64, true><<<(N + 3) / 4, 256, 0, stream>>>(bufB, row_ptr, ecol, dinv, b2, bufA, N);
    // layer 3
    gemm_lds<64, 16><<<(N + 15) / 16, 256, 0, stream>>>(bufA, W3, N, bufB);
    agg_kernel<64, true><<<(N + 3) / 4, 256, 0, stream>>>(bufB, row_ptr, ecol, dinv, b3, bufA, N);
    // layer 4 (FOUT=32, no relu, straight to d_out)
    gemm_lds<32, 32><<<(N + 31) / 32, 256, 0, stream>>>(bufA, W4, N, bufB);
    agg_kernel<32, false><<<(N + 7) / 8, 256, 0, stream>>>(bufB, row_ptr, ecol, dinv, b4, (float*)d_out, N);
}

// Round 5
// 299.571 us; speedup vs baseline: 2.1349x; 1.1103x over previous
//
#include <hip/hip_runtime.h>

#define NN 100000
#define SCAN_CHUNK 1024

typedef unsigned short ushort_t;

__device__ inline ushort_t f2bf(float f) {
    unsigned int b = __float_as_uint(f);
    unsigned int r = (b + 0x7FFFu + ((b >> 16) & 1u)) >> 16;
    return (ushort_t)r;
}
__device__ inline float bf2f(ushort_t u) {
    return __int_as_float(((unsigned int)u) << 16);
}

// ---------------- degree count ----------------
__global__ __launch_bounds__(256) void count_deg(const int* __restrict__ dst,
                                                 int* __restrict__ cnt, int E) {
    int e = blockIdx.x * 256 + threadIdx.x;
    if (e < E) atomicAdd(&cnt[dst[e]], 1);
}

// ---------------- pass 1: per-block (1024-elem chunk) sums ----------------
__global__ __launch_bounds__(256) void block_sum(const int* __restrict__ cnt,
                                                 int* __restrict__ bsum, int N) {
    __shared__ int ws[4];
    const int tid = threadIdx.x, lane = tid & 63, wid = tid >> 6;
    int i0 = blockIdx.x * SCAN_CHUNK + tid * 4;
    int s = 0;
    if (i0 + 3 < N) {
        int4 v = *(const int4*)(cnt + i0);
        s = v.x + v.y + v.z + v.w;
    } else {
#pragma unroll
        for (int j = 0; j < 4; ++j) { int i = i0 + j; if (i < N) s += cnt[i]; }
    }
#pragma unroll
    for (int off = 32; off; off >>= 1) s += __shfl_down(s, off, 64);
    if (lane == 0) ws[wid] = s;
    __syncthreads();
    if (tid == 0) bsum[blockIdx.x] = ws[0] + ws[1] + ws[2] + ws[3];
}

// ---------------- pass 2: scan the block sums (nb <= 256), write total ----------------
__global__ __launch_bounds__(256) void scan_bsums(int* __restrict__ bsum, int nb,
                                                  int* __restrict__ row_ptr, int N) {
    __shared__ int ws[4];
    const int tid = threadIdx.x, lane = tid & 63, wid = tid >> 6;
    int v = (tid < nb) ? bsum[tid] : 0;
    int x = v;
#pragma unroll
    for (int off = 1; off < 64; off <<= 1) {
        int y = __shfl_up(x, off, 64);
        if (lane >= off) x += y;
    }
    if (lane == 63) ws[wid] = x;
    __syncthreads();
    int woff = 0;
    for (int w = 0; w < wid; ++w) woff += ws[w];
    int incl = x + woff;
    if (tid < nb) bsum[tid] = incl - v;        // exclusive block offset
    if (tid == nb - 1) row_ptr[N] = incl;      // grand total = E
}

// ---------------- pass 3: local exclusive scan + block offset + deg terms ----------------
__global__ __launch_bounds__(256) void scan_final(const int* __restrict__ cnt,
                                                  const int* __restrict__ bsum,
                                                  int* __restrict__ row_ptr,
                                                  float* __restrict__ dinv_sqrt,
                                                  float* __restrict__ dinv, int N) {
    __shared__ int ws[4];
    const int tid = threadIdx.x, lane = tid & 63, wid = tid >> 6;
    int i0 = blockIdx.x * SCAN_CHUNK + tid * 4;
    int v[4];
    if (i0 + 3 < N) {
        int4 t = *(const int4*)(cnt + i0);
        v[0] = t.x; v[1] = t.y; v[2] = t.z; v[3] = t.w;
    } else {
#pragma unroll
        for (int j = 0; j < 4; ++j) { int i = i0 + j; v[j] = (i < N) ? cnt[i] : 0; }
    }
    int tsum = v[0] + v[1] + v[2] + v[3];
    int x = tsum;
#pragma unroll
    for (int off = 1; off < 64; off <<= 1) {
        int y = __shfl_up(x, off, 64);
        if (lane >= off) x += y;
    }
    if (lane == 63) ws[wid] = x;
    __syncthreads();
    int woff = 0;
    for (int w = 0; w < wid; ++w) woff += ws[w];
    int excl = bsum[blockIdx.x] + woff + (x - tsum);
#pragma unroll
    for (int j = 0; j < 4; ++j) {
        int i = i0 + j;
        if (i < N) {
            row_ptr[i] = excl;
            float deg = (float)v[j] + 1.0f;
            dinv_sqrt[i] = rsqrtf(deg);
            dinv[i] = 1.0f / deg;
        }
        excl += v[j];
    }
}

// ---------------- CSR fill: interleaved (col, norm) int2 — one 8B scattered write ----------------
__global__ __launch_bounds__(256) void fill_csr(const int* __restrict__ src,
                                                const int* __restrict__ dst,
                                                const int* __restrict__ row_ptr,
                                                int* __restrict__ fill,
                                                int2* __restrict__ ecol,
                                                const float* __restrict__ dinv_sqrt, int E) {
    int e = blockIdx.x * 256 + threadIdx.x;
    if (e >= E) return;
    int d = dst[e], s = src[e];
    int pos = row_ptr[d] + atomicAdd(&fill[d], 1);
    int2 v;
    v.x = s;
    v.y = __float_as_int(dinv_sqrt[s] * dinv_sqrt[d]);
    ecol[pos] = v;
}

// ---------------- dense GEMM h = in @ W (K=64), LDS-tiled, bf16 output ----------------
// R*FOUT == 1024: each of 256 threads computes one float4 of output (stored as 4x bf16).
template <int FOUT, int R>
__global__ __launch_bounds__(256) void gemm_lds(const float* __restrict__ in,
                                                const float* __restrict__ W, int n,
                                                ushort_t* __restrict__ h) {
    constexpr int XS = 68;  // padded x row stride (floats)
    __shared__ float xs[R * XS];
    __shared__ float ws[64 * FOUT];
    const int tid = threadIdx.x;
    const int r0 = blockIdx.x * R;
    {
        const float4* xsrc = (const float4*)(in + (size_t)r0 * 64);
        constexpr int NF4 = R * 16;
#pragma unroll
        for (int i = tid; i < NF4; i += 256) {
            int row = i >> 4, kk = (i & 15) << 2;
            float4 v = make_float4(0.f, 0.f, 0.f, 0.f);
            if (r0 + row < n) v = xsrc[i];
            *(float4*)(xs + row * XS + kk) = v;
        }
        const float4* wsrc = (const float4*)W;
#pragma unroll
        for (int i = tid; i < 64 * FOUT / 4; i += 256)
            *(float4*)(ws + i * 4) = wsrc[i];
    }
    __syncthreads();
    constexpr int CG = FOUT / 4;  // col groups per row
    const int row = tid / CG;
    const int col = (tid % CG) * 4;
    float4 acc = make_float4(0.f, 0.f, 0.f, 0.f);
#pragma unroll
    for (int k = 0; k < 64; k += 4) {
        float4 xv = *(const float4*)(xs + row * XS + k);
#pragma unroll
        for (int kk = 0; kk < 4; ++kk) {
            float a = (&xv.x)[kk];
            float4 wv = *(const float4*)(ws + (k + kk) * FOUT + col);
            acc.x = fmaf(a, wv.x, acc.x);
            acc.y = fmaf(a, wv.y, acc.y);
            acc.z = fmaf(a, wv.z, acc.z);
            acc.w = fmaf(a, wv.w, acc.w);
        }
    }
    int orow = r0 + row;
    if (orow < n) {
        ushort4 o;
        o.x = f2bf(acc.x); o.y = f2bf(acc.y); o.z = f2bf(acc.z); o.w = f2bf(acc.w);
        *(ushort4*)(h + (size_t)orow * FOUT + col) = o;
    }
}

// ---------------- aggregation: out = [relu](b + h*dinv + sum_e h[src]*norm) ----------------
// h in bf16 (half the gather bytes), fp32 accumulate; 8 gathers in flight per wave.
template <int F, bool RELU>
__global__ __launch_bounds__(256) void agg_kernel(const ushort_t* __restrict__ h,
                                                  const int* __restrict__ row_ptr,
                                                  const int2* __restrict__ ecol,
                                                  const float* __restrict__ dinv,
                                                  const float* __restrict__ b,
                                                  float* __restrict__ out, int n) {
    constexpr int GPB = 256 / F;  // node-groups per block
    int g = blockIdx.x * GPB + threadIdx.x / F;
    int f = threadIdx.x & (F - 1);
    if (g >= n) return;
    float acc = bf2f(h[(size_t)g * F + f]) * dinv[g] + b[f];
    float acc2 = 0.0f, acc3 = 0.0f, acc4 = 0.0f;
    int e0 = row_ptr[g], e1 = row_ptr[g + 1];
    int e = e0;
    for (; e + 8 <= e1; e += 8) {
        int2 c[8];
#pragma unroll
        for (int j = 0; j < 8; ++j) c[j] = ecol[e + j];
        ushort_t u[8];
#pragma unroll
        for (int j = 0; j < 8; ++j) u[j] = h[(size_t)c[j].x * F + f];
        acc  = fmaf(bf2f(u[0]), __int_as_float(c[0].y), acc);
        acc2 = fmaf(bf2f(u[1]), __int_as_float(c[1].y), acc2);
        acc3 = fmaf(bf2f(u[2]), __int_as_float(c[2].y), acc3);
        acc4 = fmaf(bf2f(u[3]), __int_as_float(c[3].y), acc4);
        acc  = fmaf(bf2f(u[4]), __int_as_float(c[4].y), acc);
        acc2 = fmaf(bf2f(u[5]), __int_as_float(c[5].y), acc2);
        acc3 = fmaf(bf2f(u[6]), __int_as_float(c[6].y), acc3);
        acc4 = fmaf(bf2f(u[7]), __int_as_float(c[7].y), acc4);
    }
    if (e + 4 <= e1) {
        int2 c[4];
#pragma unroll
        for (int j = 0; j < 4; ++j) c[j] = ecol[e + j];
        ushort_t u[4];
#pragma unroll
        for (int j = 0; j < 4; ++j) u[j] = h[(size_t)c[j].x * F + f];
        acc  = fmaf(bf2f(u[0]), __int_as_float(c[0].y), acc);
        acc2 = fmaf(bf2f(u[1]), __int_as_float(c[1].y), acc2);
        acc3 = fmaf(bf2f(u[2]), __int_as_float(c[2].y), acc3);
        acc4 = fmaf(bf2f(u[3]), __int_as_float(c[3].y), acc4);
        e += 4;
    }
    if (e + 2 <= e1) {
        int2 c0 = ecol[e], c1 = ecol[e + 1];
        float v0 = bf2f(h[(size_t)c0.x * F + f]);
        float v1 = bf2f(h[(size_t)c1.x * F + f]);
        acc  = fmaf(v0, __int_as_float(c0.y), acc);
        acc2 = fmaf(v1, __int_as_float(c1.y), acc2);
        e += 2;
    }
    if (e < e1) {
        int2 c0 = ecol[e];
        acc = fmaf(bf2f(h[(size_t)c0.x * F + f]), __int_as_float(c0.y), acc);
    }
    acc = (acc + acc2) + (acc3 + acc4);
    if (RELU) acc = fmaxf(acc, 0.0f);
    out[(size_t)g * F + f] = acc;
}

extern "C" void kernel_launch(void* const* d_in, const int* in_sizes, int n_in,
                              void* d_out, int out_size, void* d_ws, size_t ws_size,
                              hipStream_t stream) {
    const float* x  = (const float*)d_in[0];
    const int* edge = (const int*)d_in[1];
    const float* W1 = (const float*)d_in[2];
    const float* b1 = (const float*)d_in[3];
    const float* W2 = (const float*)d_in[4];
    const float* b2 = (const float*)d_in[5];
    const float* W3 = (const float*)d_in[6];
    const float* b3 = (const float*)d_in[7];
    const float* W4 = (const float*)d_in[8];
    const float* b4 = (const float*)d_in[9];

    const int N = NN;
    const int E = in_sizes[1] / 2;
    const int* src = edge;
    const int* dst = edge + E;

    char* ws = (char*)d_ws;
    size_t off = 0;
    auto alloc = [&](size_t bytes) -> void* {
        void* p = ws + off;
        off += (bytes + 255) & ~(size_t)255;
        return p;
    };
    int* cnt       = (int*)alloc((size_t)2 * N * sizeof(int));  // cnt + fill contiguous
    int* fill      = cnt + N;
    int* row_ptr   = (int*)alloc((size_t)(N + 1) * sizeof(int));
    int2* ecol     = (int2*)alloc((size_t)E * sizeof(int2));
    float* dis     = (float*)alloc((size_t)N * sizeof(float));
    float* dinv    = (float*)alloc((size_t)N * sizeof(float));
    int* bsum      = (int*)alloc((size_t)256 * sizeof(int));
    float* bufA    = (float*)alloc((size_t)N * 64 * sizeof(float));   // agg output (fp32)
    ushort_t* hb   = (ushort_t*)alloc((size_t)N * 64 * sizeof(ushort_t));  // gemm output (bf16)

    const int nb = (N + SCAN_CHUNK - 1) / SCAN_CHUNK;  // 98

    hipMemsetAsync(cnt, 0, (size_t)2 * N * sizeof(int), stream);
    count_deg<<<(E + 255) / 256, 256, 0, stream>>>(dst, cnt, E);
    block_sum<<<nb, 256, 0, stream>>>(cnt, bsum, N);
    scan_bsums<<<1, 256, 0, stream>>>(bsum, nb, row_ptr, N);
    scan_final<<<nb, 256, 0, stream>>>(cnt, bsum, row_ptr, dis, dinv, N);
    fill_csr<<<(E + 255) / 256, 256, 0, stream>>>(src, dst, row_ptr, fill, ecol, dis, E);

    // layer 1
    gemm_lds<64, 16><<<(N + 15) / 16, 256, 0, stream>>>(x, W1, N, hb);
    agg_kernel<64, true><<<(N + 3) / 4, 256, 0, stream>>>(hb, row_ptr, ecol, dinv, b1, bufA, N);
    // layer 2
    gemm_lds<64, 16><<<(N + 15) / 16, 256, 0, stream>>>(bufA, W2, N, hb);
    agg_kernel<64, true><<<(N + 3) / 4, 256, 0, stream>>>(hb, row_ptr, ecol, dinv, b2, bufA, N);
    // layer 3
    gemm_lds<64, 16><<<(N + 15) / 16, 256, 0, stream>>>(bufA, W3, N, hb);
    agg_kernel<64, true><<<(N + 3) / 4, 256, 0, stream>>>(hb, row_ptr, ecol, dinv, b3, bufA, N);
    // layer 4 (FOUT=32, no relu, straight to d_out)
    gemm_lds<32, 32><<<(N + 31) / 32, 256, 0, stream>>>(bufA, W4, N, hb);
    agg_kernel<32, false><<<(N + 7) / 8, 256, 0, stream>>>(hb, row_ptr, ecol, dinv, b4, (float*)d_out, N);
}

// Round 6
// 285.714 us; speedup vs baseline: 2.2384x; 1.0485x over previous
//
#include <hip/hip_runtime.h>

#define NN 100000
#define SCAN_CHUNK 1024
#define EPB 1024   // edges per fill_csr block
#define NPASS 8

typedef unsigned short ushort_t;

__device__ inline ushort_t f2bf(float f) {
    unsigned int b = __float_as_uint(f);
    unsigned int r = (b + 0x7FFFu + ((b >> 16) & 1u)) >> 16;
    return (ushort_t)r;
}
__device__ inline float bf2f(ushort_t u) {
    return __int_as_float(((unsigned int)u) << 16);
}

// ---------------- zero workspace ints ----------------
__global__ __launch_bounds__(256) void zero_int4(int4* __restrict__ p, int n4) {
    int i = blockIdx.x * 256 + threadIdx.x;
    if (i < n4) p[i] = make_int4(0, 0, 0, 0);
}

// ---------------- degree count ----------------
__global__ __launch_bounds__(256) void count_deg(const int* __restrict__ dst,
                                                 int* __restrict__ cnt, int E) {
    int e = blockIdx.x * 256 + threadIdx.x;
    if (e < E) atomicAdd(&cnt[dst[e]], 1);
}

// ---------------- pass 1: per-block (1024-elem chunk) sums ----------------
__global__ __launch_bounds__(256) void block_sum(const int* __restrict__ cnt,
                                                 int* __restrict__ bsum, int N) {
    __shared__ int ws[4];
    const int tid = threadIdx.x, lane = tid & 63, wid = tid >> 6;
    int i0 = blockIdx.x * SCAN_CHUNK + tid * 4;
    int s = 0;
    if (i0 + 3 < N) {
        int4 v = *(const int4*)(cnt + i0);
        s = v.x + v.y + v.z + v.w;
    } else {
#pragma unroll
        for (int j = 0; j < 4; ++j) { int i = i0 + j; if (i < N) s += cnt[i]; }
    }
#pragma unroll
    for (int off = 32; off; off >>= 1) s += __shfl_down(s, off, 64);
    if (lane == 0) ws[wid] = s;
    __syncthreads();
    if (tid == 0) bsum[blockIdx.x] = ws[0] + ws[1] + ws[2] + ws[3];
}

// ---------------- pass 2: scan the block sums (nb <= 256), write total ----------------
__global__ __launch_bounds__(256) void scan_bsums(int* __restrict__ bsum, int nb,
                                                  int* __restrict__ row_ptr, int N) {
    __shared__ int ws[4];
    const int tid = threadIdx.x, lane = tid & 63, wid = tid >> 6;
    int v = (tid < nb) ? bsum[tid] : 0;
    int x = v;
#pragma unroll
    for (int off = 1; off < 64; off <<= 1) {
        int y = __shfl_up(x, off, 64);
        if (lane >= off) x += y;
    }
    if (lane == 63) ws[wid] = x;
    __syncthreads();
    int woff = 0;
    for (int w = 0; w < wid; ++w) woff += ws[w];
    int incl = x + woff;
    if (tid < nb) bsum[tid] = incl - v;        // exclusive block offset
    if (tid == nb - 1) row_ptr[N] = incl;      // grand total = E
}

// ---------------- pass 3: local exclusive scan + block offset + deg terms ----------------
__global__ __launch_bounds__(256) void scan_final(const int* __restrict__ cnt,
                                                  const int* __restrict__ bsum,
                                                  int* __restrict__ row_ptr,
                                                  float* __restrict__ dinv_sqrt,
                                                  float* __restrict__ dinv, int N) {
    __shared__ int ws[4];
    const int tid = threadIdx.x, lane = tid & 63, wid = tid >> 6;
    int i0 = blockIdx.x * SCAN_CHUNK + tid * 4;
    int v[4];
    if (i0 + 3 < N) {
        int4 t = *(const int4*)(cnt + i0);
        v[0] = t.x; v[1] = t.y; v[2] = t.z; v[3] = t.w;
    } else {
#pragma unroll
        for (int j = 0; j < 4; ++j) { int i = i0 + j; v[j] = (i < N) ? cnt[i] : 0; }
    }
    int tsum = v[0] + v[1] + v[2] + v[3];
    int x = tsum;
#pragma unroll
    for (int off = 1; off < 64; off <<= 1) {
        int y = __shfl_up(x, off, 64);
        if (lane >= off) x += y;
    }
    if (lane == 63) ws[wid] = x;
    __syncthreads();
    int woff = 0;
    for (int w = 0; w < wid; ++w) woff += ws[w];
    int excl = bsum[blockIdx.x] + woff + (x - tsum);
#pragma unroll
    for (int j = 0; j < 4; ++j) {
        int i = i0 + j;
        if (i < N) {
            row_ptr[i] = excl;
            float deg = (float)v[j] + 1.0f;
            dinv_sqrt[i] = rsqrtf(deg);
            dinv[i] = 1.0f / deg;
        }
        excl += v[j];
    }
}

// ---------------- CSR fill: LDS-chunked, 8 dst-range passes for write locality ----------------
// Each block caches EPB edges in LDS, then 8 passes each scatter only dst in a 1/8 range.
// Blocks progress through passes ~in lockstep -> scattered writes stay in an ~800KB
// window -> L2-resident -> full-line packing (kills the 8.5x write amplification).
__global__ __launch_bounds__(256) void fill_csr(const int* __restrict__ src,
                                                const int* __restrict__ dst,
                                                const int* __restrict__ row_ptr,
                                                int* __restrict__ fill,
                                                int2* __restrict__ ecol,
                                                const float* __restrict__ dinv_sqrt, int E) {
    __shared__ int sd[EPB];
    __shared__ int ss[EPB];
    __shared__ float sn[EPB];
    const int base = blockIdx.x * EPB;
    const int cnt = min(EPB, E - base);
    for (int i = threadIdx.x; i < cnt; i += 256) {
        int e = base + i;
        int s = src[e], d = dst[e];
        sd[i] = d; ss[i] = s;
        sn[i] = dinv_sqrt[s] * dinv_sqrt[d];
    }
    __syncthreads();
    const int RANGE = (NN + NPASS - 1) / NPASS;  // 12500
    for (int p = 0; p < NPASS; ++p) {
        int lo = p * RANGE, hi = lo + RANGE;
        for (int i = threadIdx.x; i < cnt; i += 256) {
            int d = sd[i];
            if (d >= lo && d < hi) {
                int pos = row_ptr[d] + atomicAdd(&fill[d], 1);
                int2 v; v.x = ss[i]; v.y = __float_as_int(sn[i]);
                ecol[pos] = v;
            }
        }
        __syncthreads();
    }
}

// ---------------- shared edge-aggregation body (h bf16, 8 gathers in flight) ----------------
template <int F>
__device__ inline float agg_edges(const ushort_t* __restrict__ h,
                                  const int2* __restrict__ ecol,
                                  int e0, int e1, int f, float acc) {
    float acc2 = 0.0f, acc3 = 0.0f, acc4 = 0.0f;
    int e = e0;
    for (; e + 8 <= e1; e += 8) {
        int2 c[8];
#pragma unroll
        for (int j = 0; j < 8; ++j) c[j] = ecol[e + j];
        ushort_t u[8];
#pragma unroll
        for (int j = 0; j < 8; ++j) u[j] = h[(size_t)c[j].x * F + f];
        acc  = fmaf(bf2f(u[0]), __int_as_float(c[0].y), acc);
        acc2 = fmaf(bf2f(u[1]), __int_as_float(c[1].y), acc2);
        acc3 = fmaf(bf2f(u[2]), __int_as_float(c[2].y), acc3);
        acc4 = fmaf(bf2f(u[3]), __int_as_float(c[3].y), acc4);
        acc  = fmaf(bf2f(u[4]), __int_as_float(c[4].y), acc);
        acc2 = fmaf(bf2f(u[5]), __int_as_float(c[5].y), acc2);
        acc3 = fmaf(bf2f(u[6]), __int_as_float(c[6].y), acc3);
        acc4 = fmaf(bf2f(u[7]), __int_as_float(c[7].y), acc4);
    }
    if (e + 4 <= e1) {
        int2 c[4];
#pragma unroll
        for (int j = 0; j < 4; ++j) c[j] = ecol[e + j];
        ushort_t u[4];
#pragma unroll
        for (int j = 0; j < 4; ++j) u[j] = h[(size_t)c[j].x * F + f];
        acc  = fmaf(bf2f(u[0]), __int_as_float(c[0].y), acc);
        acc2 = fmaf(bf2f(u[1]), __int_as_float(c[1].y), acc2);
        acc3 = fmaf(bf2f(u[2]), __int_as_float(c[2].y), acc3);
        acc4 = fmaf(bf2f(u[3]), __int_as_float(c[3].y), acc4);
        e += 4;
    }
    if (e + 2 <= e1) {
        int2 c0 = ecol[e], c1 = ecol[e + 1];
        acc  = fmaf(bf2f(h[(size_t)c0.x * F + f]), __int_as_float(c0.y), acc);
        acc2 = fmaf(bf2f(h[(size_t)c1.x * F + f]), __int_as_float(c1.y), acc2);
        e += 2;
    }
    if (e < e1) {
        int2 c0 = ecol[e];
        acc = fmaf(bf2f(h[(size_t)c0.x * F + f]), __int_as_float(c0.y), acc);
    }
    return (acc + acc2) + (acc3 + acc4);
}

// ---------------- dense GEMM h = in @ W (K=64), LDS-tiled, bf16 output ----------------
template <int FOUT, int R>
__global__ __launch_bounds__(256) void gemm_lds(const float* __restrict__ in,
                                                const float* __restrict__ W, int n,
                                                ushort_t* __restrict__ h) {
    constexpr int XS = 68;
    __shared__ float xs[R * XS];
    __shared__ float ws[64 * FOUT];
    const int tid = threadIdx.x;
    const int r0 = blockIdx.x * R;
    {
        const float4* xsrc = (const float4*)(in + (size_t)r0 * 64);
        constexpr int NF4 = R * 16;
#pragma unroll
        for (int i = tid; i < NF4; i += 256) {
            int row = i >> 4, kk = (i & 15) << 2;
            float4 v = make_float4(0.f, 0.f, 0.f, 0.f);
            if (r0 + row < n) v = xsrc[i];
            *(float4*)(xs + row * XS + kk) = v;
        }
        const float4* wsrc = (const float4*)W;
#pragma unroll
        for (int i = tid; i < 64 * FOUT / 4; i += 256)
            *(float4*)(ws + i * 4) = wsrc[i];
    }
    __syncthreads();
    constexpr int CG = FOUT / 4;
    const int row = tid / CG;
    const int col = (tid % CG) * 4;
    float4 acc = make_float4(0.f, 0.f, 0.f, 0.f);
#pragma unroll
    for (int k = 0; k < 64; k += 4) {
        float4 xv = *(const float4*)(xs + row * XS + k);
#pragma unroll
        for (int kk = 0; kk < 4; ++kk) {
            float a = (&xv.x)[kk];
            float4 wv = *(const float4*)(ws + (k + kk) * FOUT + col);
            acc.x = fmaf(a, wv.x, acc.x);
            acc.y = fmaf(a, wv.y, acc.y);
            acc.z = fmaf(a, wv.z, acc.z);
            acc.w = fmaf(a, wv.w, acc.w);
        }
    }
    int orow = r0 + row;
    if (orow < n) {
        ushort4 o;
        o.x = f2bf(acc.x); o.y = f2bf(acc.y); o.z = f2bf(acc.z); o.w = f2bf(acc.w);
        *(ushort4*)(h + (size_t)orow * FOUT + col) = o;
    }
}

// ---------------- FUSED: agg(layer i, F_IN=64, relu) -> LDS -> gemm(layer i+1) ----------------
// Block handles R contiguous rows; wave w aggregates rows [w*R/4, (w+1)*R/4), f = lane.
template <int FOUT, int R>
__global__ __launch_bounds__(256) void agg_gemm(const ushort_t* __restrict__ hin,
                                                const int* __restrict__ row_ptr,
                                                const int2* __restrict__ ecol,
                                                const float* __restrict__ dinv,
                                                const float* __restrict__ bagg,
                                                const float* __restrict__ W, int n,
                                                ushort_t* __restrict__ hout) {
    constexpr int XS = 68;
    __shared__ float xs[R * XS];
    __shared__ float ws[64 * FOUT];
    const int tid = threadIdx.x, lane = tid & 63, wid = tid >> 6;
    const int r0 = blockIdx.x * R;
    // stage W
    const float4* wsrc = (const float4*)W;
#pragma unroll
    for (int i = tid; i < 64 * FOUT / 4; i += 256)
        *(float4*)(ws + i * 4) = wsrc[i];
    // phase A: aggregate R rows (relu'd, fp32) into xs
    constexpr int RPW = R / 4;
#pragma unroll 1
    for (int rr = 0; rr < RPW; ++rr) {
        int row = wid * RPW + rr;
        int g = r0 + row;
        if (g < n) {
            float acc = bf2f(hin[(size_t)g * 64 + lane]) * dinv[g] + bagg[lane];
            acc = agg_edges<64>(hin, ecol, row_ptr[g], row_ptr[g + 1], lane, acc);
            xs[row * XS + lane] = fmaxf(acc, 0.0f);
        }
    }
    __syncthreads();
    // phase B: gemm from xs
    constexpr int CG = FOUT / 4;
    const int row = tid / CG;
    const int col = (tid % CG) * 4;
    float4 acc = make_float4(0.f, 0.f, 0.f, 0.f);
#pragma unroll
    for (int k = 0; k < 64; k += 4) {
        float4 xv = *(const float4*)(xs + row * XS + k);
#pragma unroll
        for (int kk = 0; kk < 4; ++kk) {
            float a = (&xv.x)[kk];
            float4 wv = *(const float4*)(ws + (k + kk) * FOUT + col);
            acc.x = fmaf(a, wv.x, acc.x);
            acc.y = fmaf(a, wv.y, acc.y);
            acc.z = fmaf(a, wv.z, acc.z);
            acc.w = fmaf(a, wv.w, acc.w);
        }
    }
    int orow = r0 + row;
    if (orow < n) {
        ushort4 o;
        o.x = f2bf(acc.x); o.y = f2bf(acc.y); o.z = f2bf(acc.z); o.w = f2bf(acc.w);
        *(ushort4*)(hout + (size_t)orow * FOUT + col) = o;
    }
}

// ---------------- final aggregation (F=32, no relu, fp32 out) ----------------
template <int F, bool RELU>
__global__ __launch_bounds__(256) void agg_kernel(const ushort_t* __restrict__ h,
                                                  const int* __restrict__ row_ptr,
                                                  const int2* __restrict__ ecol,
                                                  const float* __restrict__ dinv,
                                                  const float* __restrict__ b,
                                                  float* __restrict__ out, int n) {
    constexpr int GPB = 256 / F;
    int g = blockIdx.x * GPB + threadIdx.x / F;
    int f = threadIdx.x & (F - 1);
    if (g >= n) return;
    float acc = bf2f(h[(size_t)g * F + f]) * dinv[g] + b[f];
    acc = agg_edges<F>(h, ecol, row_ptr[g], row_ptr[g + 1], f, acc);
    if (RELU) acc = fmaxf(acc, 0.0f);
    out[(size_t)g * F + f] = acc;
}

extern "C" void kernel_launch(void* const* d_in, const int* in_sizes, int n_in,
                              void* d_out, int out_size, void* d_ws, size_t ws_size,
                              hipStream_t stream) {
    const float* x  = (const float*)d_in[0];
    const int* edge = (const int*)d_in[1];
    const float* W1 = (const float*)d_in[2];
    const float* b1 = (const float*)d_in[3];
    const float* W2 = (const float*)d_in[4];
    const float* b2 = (const float*)d_in[5];
    const float* W3 = (const float*)d_in[6];
    const float* b3 = (const float*)d_in[7];
    const float* W4 = (const float*)d_in[8];
    const float* b4 = (const float*)d_in[9];

    const int N = NN;
    const int E = in_sizes[1] / 2;
    const int* src = edge;
    const int* dst = edge + E;

    char* ws = (char*)d_ws;
    size_t off = 0;
    auto alloc = [&](size_t bytes) -> void* {
        void* p = ws + off;
        off += (bytes + 255) & ~(size_t)255;
        return p;
    };
    int* cnt       = (int*)alloc((size_t)2 * N * sizeof(int));  // cnt + fill contiguous
    int* fill      = cnt + N;
    int* row_ptr   = (int*)alloc((size_t)(N + 1) * sizeof(int));
    int2* ecol     = (int2*)alloc((size_t)E * sizeof(int2));
    float* dis     = (float*)alloc((size_t)N * sizeof(float));
    float* dinv    = (float*)alloc((size_t)N * sizeof(float));
    int* bsum      = (int*)alloc((size_t)256 * sizeof(int));
    ushort_t* hbA  = (ushort_t*)alloc((size_t)N * 64 * sizeof(ushort_t));
    ushort_t* hbB  = (ushort_t*)alloc((size_t)N * 64 * sizeof(ushort_t));

    const int nb = (N + SCAN_CHUNK - 1) / SCAN_CHUNK;  // 98
    const int n4 = (2 * N + 3) / 4;                    // int4s to zero

    zero_int4<<<(n4 + 255) / 256, 256, 0, stream>>>((int4*)cnt, n4);
    count_deg<<<(E + 255) / 256, 256, 0, stream>>>(dst, cnt, E);
    block_sum<<<nb, 256, 0, stream>>>(cnt, bsum, N);
    scan_bsums<<<1, 256, 0, stream>>>(bsum, nb, row_ptr, N);
    scan_final<<<nb, 256, 0, stream>>>(cnt, bsum, row_ptr, dis, dinv, N);
    fill_csr<<<(E + EPB - 1) / EPB, 256, 0, stream>>>(src, dst, row_ptr, fill, ecol, dis, E);

    // layer 1 GEMM: x (fp32) @ W1 -> hbA (bf16)
    gemm_lds<64, 16><<<(N + 15) / 16, 256, 0, stream>>>(x, W1, N, hbA);
    // fused agg1+gemm2, agg2+gemm3, agg3+gemm4
    agg_gemm<64, 16><<<(N + 15) / 16, 256, 0, stream>>>(hbA, row_ptr, ecol, dinv, b1, W2, N, hbB);
    agg_gemm<64, 16><<<(N + 15) / 16, 256, 0, stream>>>(hbB, row_ptr, ecol, dinv, b2, W3, N, hbA);
    agg_gemm<32, 32><<<(N + 31) / 32, 256, 0, stream>>>(hbA, row_ptr, ecol, dinv, b3, W4, N, hbB);
    // final aggregation (F=32) -> d_out fp32
    agg_kernel<32, false><<<(N + 7) / 8, 256, 0, stream>>>(hbB, row_ptr, ecol, dinv, b4, (float*)d_out, N);
}

// Round 8
// 240.033 us; speedup vs baseline: 2.6644x; 1.1903x over previous
//
#include <hip/hip_runtime.h>

#define NN 100000
#define SCAN_CHUNK 1024
#define EPB 1024   // edges per fill_csr block
#define NPASS 8

typedef unsigned short ushort_t;

__device__ inline ushort_t f2bf(float f) {
    unsigned int b = __float_as_uint(f);
    unsigned int r = (b + 0x7FFFu + ((b >> 16) & 1u)) >> 16;
    return (ushort_t)r;
}
__device__ inline float bf2f(ushort_t u) {
    return __int_as_float(((unsigned int)u) << 16);
}

// ---------------- zero workspace ints ----------------
__global__ __launch_bounds__(256) void zero_int4(int4* __restrict__ p, int n4) {
    int i = blockIdx.x * 256 + threadIdx.x;
    if (i < n4) p[i] = make_int4(0, 0, 0, 0);
}

// ---------------- degree count ----------------
__global__ __launch_bounds__(256) void count_deg(const int* __restrict__ dst,
                                                 int* __restrict__ cnt, int E) {
    int e = blockIdx.x * 256 + threadIdx.x;
    if (e < E) atomicAdd(&cnt[dst[e]], 1);
}

// ---------------- pass 1: per-block (1024-elem chunk) sums ----------------
__global__ __launch_bounds__(256) void block_sum(const int* __restrict__ cnt,
                                                 int* __restrict__ bsum, int N) {
    __shared__ int ws[4];
    const int tid = threadIdx.x, lane = tid & 63, wid = tid >> 6;
    int i0 = blockIdx.x * SCAN_CHUNK + tid * 4;
    int s = 0;
    if (i0 + 3 < N) {
        int4 v = *(const int4*)(cnt + i0);
        s = v.x + v.y + v.z + v.w;
    } else {
#pragma unroll
        for (int j = 0; j < 4; ++j) { int i = i0 + j; if (i < N) s += cnt[i]; }
    }
#pragma unroll
    for (int off = 32; off; off >>= 1) s += __shfl_down(s, off, 64);
    if (lane == 0) ws[wid] = s;
    __syncthreads();
    if (tid == 0) bsum[blockIdx.x] = ws[0] + ws[1] + ws[2] + ws[3];
}

// ---------------- pass 2: scan the block sums (nb <= 256), write total ----------------
__global__ __launch_bounds__(256) void scan_bsums(int* __restrict__ bsum, int nb,
                                                  int* __restrict__ row_ptr, int N) {
    __shared__ int ws[4];
    const int tid = threadIdx.x, lane = tid & 63, wid = tid >> 6;
    int v = (tid < nb) ? bsum[tid] : 0;
    int x = v;
#pragma unroll
    for (int off = 1; off < 64; off <<= 1) {
        int y = __shfl_up(x, off, 64);
        if (lane >= off) x += y;
    }
    if (lane == 63) ws[wid] = x;
    __syncthreads();
    int woff = 0;
    for (int w = 0; w < wid; ++w) woff += ws[w];
    int incl = x + woff;
    if (tid < nb) bsum[tid] = incl - v;        // exclusive block offset
    if (tid == nb - 1) row_ptr[N] = incl;      // grand total = E
}

// ---------------- pass 3: local exclusive scan + block offset + deg terms ----------------
__global__ __launch_bounds__(256) void scan_final(const int* __restrict__ cnt,
                                                  const int* __restrict__ bsum,
                                                  int* __restrict__ row_ptr,
                                                  float* __restrict__ dinv_sqrt,
                                                  float* __restrict__ dinv, int N) {
    __shared__ int ws[4];
    const int tid = threadIdx.x, lane = tid & 63, wid = tid >> 6;
    int i0 = blockIdx.x * SCAN_CHUNK + tid * 4;
    int v[4];
    if (i0 + 3 < N) {
        int4 t = *(const int4*)(cnt + i0);
        v[0] = t.x; v[1] = t.y; v[2] = t.z; v[3] = t.w;
    } else {
#pragma unroll
        for (int j = 0; j < 4; ++j) { int i = i0 + j; v[j] = (i < N) ? cnt[i] : 0; }
    }
    int tsum = v[0] + v[1] + v[2] + v[3];
    int x = tsum;
#pragma unroll
    for (int off = 1; off < 64; off <<= 1) {
        int y = __shfl_up(x, off, 64);
        if (lane >= off) x += y;
    }
    if (lane == 63) ws[wid] = x;
    __syncthreads();
    int woff = 0;
    for (int w = 0; w < wid; ++w) woff += ws[w];
    int excl = bsum[blockIdx.x] + woff + (x - tsum);
#pragma unroll
    for (int j = 0; j < 4; ++j) {
        int i = i0 + j;
        if (i < N) {
            row_ptr[i] = excl;
            float deg = (float)v[j] + 1.0f;
            dinv_sqrt[i] = rsqrtf(deg);
            dinv[i] = 1.0f / deg;
        }
        excl += v[j];
    }
}

// ---------------- CSR fill: LDS-chunked, 8 dst-range passes for write locality ----------------
__global__ __launch_bounds__(256) void fill_csr(const int* __restrict__ src,
                                                const int* __restrict__ dst,
                                                const int* __restrict__ row_ptr,
                                                int* __restrict__ fill,
                                                int2* __restrict__ ecol,
                                                const float* __restrict__ dinv_sqrt, int E) {
    __shared__ int sd[EPB];
    __shared__ int ss[EPB];
    __shared__ float sn[EPB];
    const int base = blockIdx.x * EPB;
    const int cnt = min(EPB, E - base);
    for (int i = threadIdx.x; i < cnt; i += 256) {
        int e = base + i;
        int s = src[e], d = dst[e];
        sd[i] = d; ss[i] = s;
        sn[i] = dinv_sqrt[s] * dinv_sqrt[d];
    }
    __syncthreads();
    const int RANGE = (NN + NPASS - 1) / NPASS;  // 12500
    for (int p = 0; p < NPASS; ++p) {
        int lo = p * RANGE, hi = lo + RANGE;
        for (int i = threadIdx.x; i < cnt; i += 256) {
            int d = sd[i];
            if (d >= lo && d < hi) {
                int pos = row_ptr[d] + atomicAdd(&fill[d], 1);
                int2 v; v.x = ss[i]; v.y = __float_as_int(sn[i]);
                ecol[pos] = v;
            }
        }
        __syncthreads();
    }
}

// ---------------- vectorized edge aggregation: 4 features/lane (ushort4 gather) ----------------
template <int F>
__device__ inline float4 agg_edges_v4(const ushort_t* __restrict__ h,
                                      const int2* __restrict__ ecol,
                                      int e0, int e1, int fbase, float4 acc) {
    float4 accB = make_float4(0.f, 0.f, 0.f, 0.f);
    int e = e0;
    for (; e + 8 <= e1; e += 8) {
        int2 c[8];
#pragma unroll
        for (int j = 0; j < 8; ++j) c[j] = ecol[e + j];
        ushort4 u[8];
#pragma unroll
        for (int j = 0; j < 8; ++j) u[j] = *(const ushort4*)(h + (size_t)c[j].x * F + fbase);
#pragma unroll
        for (int j = 0; j < 8; j += 2) {
            float n0 = __int_as_float(c[j].y);
            float n1 = __int_as_float(c[j + 1].y);
            acc.x  = fmaf(bf2f(u[j].x), n0, acc.x);
            acc.y  = fmaf(bf2f(u[j].y), n0, acc.y);
            acc.z  = fmaf(bf2f(u[j].z), n0, acc.z);
            acc.w  = fmaf(bf2f(u[j].w), n0, acc.w);
            accB.x = fmaf(bf2f(u[j + 1].x), n1, accB.x);
            accB.y = fmaf(bf2f(u[j + 1].y), n1, accB.y);
            accB.z = fmaf(bf2f(u[j + 1].z), n1, accB.z);
            accB.w = fmaf(bf2f(u[j + 1].w), n1, accB.w);
        }
    }
    if (e + 4 <= e1) {
        int2 c[4];
#pragma unroll
        for (int j = 0; j < 4; ++j) c[j] = ecol[e + j];
        ushort4 u[4];
#pragma unroll
        for (int j = 0; j < 4; ++j) u[j] = *(const ushort4*)(h + (size_t)c[j].x * F + fbase);
#pragma unroll
        for (int j = 0; j < 4; j += 2) {
            float n0 = __int_as_float(c[j].y);
            float n1 = __int_as_float(c[j + 1].y);
            acc.x  = fmaf(bf2f(u[j].x), n0, acc.x);
            acc.y  = fmaf(bf2f(u[j].y), n0, acc.y);
            acc.z  = fmaf(bf2f(u[j].z), n0, acc.z);
            acc.w  = fmaf(bf2f(u[j].w), n0, acc.w);
            accB.x = fmaf(bf2f(u[j + 1].x), n1, accB.x);
            accB.y = fmaf(bf2f(u[j + 1].y), n1, accB.y);
            accB.z = fmaf(bf2f(u[j + 1].z), n1, accB.z);
            accB.w = fmaf(bf2f(u[j + 1].w), n1, accB.w);
        }
        e += 4;
    }
    for (; e < e1; ++e) {
        int2 c = ecol[e];
        ushort4 u = *(const ushort4*)(h + (size_t)c.x * F + fbase);
        float nv = __int_as_float(c.y);
        acc.x = fmaf(bf2f(u.x), nv, acc.x);
        acc.y = fmaf(bf2f(u.y), nv, acc.y);
        acc.z = fmaf(bf2f(u.z), nv, acc.z);
        acc.w = fmaf(bf2f(u.w), nv, acc.w);
    }
    acc.x += accB.x; acc.y += accB.y; acc.z += accB.z; acc.w += accB.w;
    return acc;
}

// self-loop + bias init for a 4-feature slice
template <int F>
__device__ inline float4 agg_self(const ushort_t* __restrict__ h, int g, float dv,
                                  const float* __restrict__ b, int fbase) {
    ushort4 u = *(const ushort4*)(h + (size_t)g * F + fbase);
    float4 a;
    a.x = fmaf(bf2f(u.x), dv, b[fbase + 0]);
    a.y = fmaf(bf2f(u.y), dv, b[fbase + 1]);
    a.z = fmaf(bf2f(u.z), dv, b[fbase + 2]);
    a.w = fmaf(bf2f(u.w), dv, b[fbase + 3]);
    return a;
}

// ---------------- dense GEMM h = in @ W (K=64), LDS-tiled, bf16 output ----------------
template <int FOUT, int R>
__global__ __launch_bounds__(256) void gemm_lds(const float* __restrict__ in,
                                                const float* __restrict__ W, int n,
                                                ushort_t* __restrict__ h) {
    constexpr int XS = 68;
    __shared__ float xs[R * XS];
    __shared__ float ws[64 * FOUT];
    const int tid = threadIdx.x;
    const int r0 = blockIdx.x * R;
    {
        const float4* xsrc = (const float4*)(in + (size_t)r0 * 64);
        constexpr int NF4 = R * 16;
#pragma unroll
        for (int i = tid; i < NF4; i += 256) {
            int row = i >> 4, kk = (i & 15) << 2;
            float4 v = make_float4(0.f, 0.f, 0.f, 0.f);
            if (r0 + row < n) v = xsrc[i];
            *(float4*)(xs + row * XS + kk) = v;
        }
        const float4* wsrc = (const float4*)W;
#pragma unroll
        for (int i = tid; i < 64 * FOUT / 4; i += 256)
            *(float4*)(ws + i * 4) = wsrc[i];
    }
    __syncthreads();
    constexpr int CG = FOUT / 4;
    const int row = tid / CG;
    const int col = (tid % CG) * 4;
    float4 acc = make_float4(0.f, 0.f, 0.f, 0.f);
#pragma unroll
    for (int k = 0; k < 64; k += 4) {
        float4 xv = *(const float4*)(xs + row * XS + k);
#pragma unroll
        for (int kk = 0; kk < 4; ++kk) {
            float a = (&xv.x)[kk];
            float4 wv = *(const float4*)(ws + (k + kk) * FOUT + col);
            acc.x = fmaf(a, wv.x, acc.x);
            acc.y = fmaf(a, wv.y, acc.y);
            acc.z = fmaf(a, wv.z, acc.z);
            acc.w = fmaf(a, wv.w, acc.w);
        }
    }
    int orow = r0 + row;
    if (orow < n) {
        ushort4 o;
        o.x = f2bf(acc.x); o.y = f2bf(acc.y); o.z = f2bf(acc.z); o.w = f2bf(acc.w);
        *(ushort4*)(h + (size_t)orow * FOUT + col) = o;
    }
}

// ---------------- FUSED: agg(F_IN=64, relu) -> LDS -> gemm(next layer) ----------------
// agg phase: 16 lanes per row (4 features/lane), 4 rows per wave concurrently,
// R=16 rows/block -> 32 outstanding gathers per wave.
// phase B guard row < R: for FOUT=32 only half the threads produce output.
template <int FOUT>
__global__ __launch_bounds__(256) void agg_gemm(const ushort_t* __restrict__ hin,
                                                const int* __restrict__ row_ptr,
                                                const int2* __restrict__ ecol,
                                                const float* __restrict__ dinv,
                                                const float* __restrict__ bagg,
                                                const float* __restrict__ W, int n,
                                                ushort_t* __restrict__ hout) {
    constexpr int R = 16;
    constexpr int XS = 68;
    __shared__ float xs[R * XS];
    __shared__ float ws[64 * FOUT];
    const int tid = threadIdx.x, lane = tid & 63, wid = tid >> 6;
    const int r0 = blockIdx.x * R;
    // stage W
    const float4* wsrc = (const float4*)W;
#pragma unroll
    for (int i = tid; i < 64 * FOUT / 4; i += 256)
        *(float4*)(ws + i * 4) = wsrc[i];
    // phase A: aggregate (4 rows per wave in parallel)
    {
        const int sub = lane >> 4;         // row within wave's quad
        const int fbase = (lane & 15) * 4; // feature slice
        const int row = wid * 4 + sub;
        const int g = r0 + row;
        if (g < n) {
            float4 acc = agg_self<64>(hin, g, dinv[g], bagg, fbase);
            acc = agg_edges_v4<64>(hin, ecol, row_ptr[g], row_ptr[g + 1], fbase, acc);
            float4 r;
            r.x = fmaxf(acc.x, 0.f); r.y = fmaxf(acc.y, 0.f);
            r.z = fmaxf(acc.z, 0.f); r.w = fmaxf(acc.w, 0.f);
            *(float4*)(xs + row * XS + fbase) = r;
        }
    }
    __syncthreads();
    // phase B: gemm from xs (only rows < R are valid/needed)
    constexpr int CG = FOUT / 4;
    const int row = tid / CG;
    const int col = (tid % CG) * 4;
    if (row < R) {
        float4 acc = make_float4(0.f, 0.f, 0.f, 0.f);
#pragma unroll
        for (int k = 0; k < 64; k += 4) {
            float4 xv = *(const float4*)(xs + row * XS + k);
#pragma unroll
            for (int kk = 0; kk < 4; ++kk) {
                float a = (&xv.x)[kk];
                float4 wv = *(const float4*)(ws + (k + kk) * FOUT + col);
                acc.x = fmaf(a, wv.x, acc.x);
                acc.y = fmaf(a, wv.y, acc.y);
                acc.z = fmaf(a, wv.z, acc.z);
                acc.w = fmaf(a, wv.w, acc.w);
            }
        }
        int orow = r0 + row;
        if (orow < n) {
            ushort4 o;
            o.x = f2bf(acc.x); o.y = f2bf(acc.y); o.z = f2bf(acc.z); o.w = f2bf(acc.w);
            *(ushort4*)(hout + (size_t)orow * FOUT + col) = o;
        }
    }
}

// ---------------- final aggregation (F=32, fp32 out): 8 lanes/row, 8 rows/wave ----------------
__global__ __launch_bounds__(256) void agg_final(const ushort_t* __restrict__ h,
                                                 const int* __restrict__ row_ptr,
                                                 const int2* __restrict__ ecol,
                                                 const float* __restrict__ dinv,
                                                 const float* __restrict__ b,
                                                 float* __restrict__ out, int n) {
    const int tid = threadIdx.x, lane = tid & 63, wid = tid >> 6;
    const int sub = lane >> 3;         // 0..7
    const int fbase = (lane & 7) * 4;
    int g = blockIdx.x * 32 + wid * 8 + sub;
    if (g >= n) return;
    float4 acc = agg_self<32>(h, g, dinv[g], b, fbase);
    acc = agg_edges_v4<32>(h, ecol, row_ptr[g], row_ptr[g + 1], fbase, acc);
    *(float4*)(out + (size_t)g * 32 + fbase) = acc;
}

extern "C" void kernel_launch(void* const* d_in, const int* in_sizes, int n_in,
                              void* d_out, int out_size, void* d_ws, size_t ws_size,
                              hipStream_t stream) {
    const float* x  = (const float*)d_in[0];
    const int* edge = (const int*)d_in[1];
    const float* W1 = (const float*)d_in[2];
    const float* b1 = (const float*)d_in[3];
    const float* W2 = (const float*)d_in[4];
    const float* b2 = (const float*)d_in[5];
    const float* W3 = (const float*)d_in[6];
    const float* b3 = (const float*)d_in[7];
    const float* W4 = (const float*)d_in[8];
    const float* b4 = (const float*)d_in[9];

    const int N = NN;
    const int E = in_sizes[1] / 2;
    const int* src = edge;
    const int* dst = edge + E;

    char* ws = (char*)d_ws;
    size_t off = 0;
    auto alloc = [&](size_t bytes) -> void* {
        void* p = ws + off;
        off += (bytes + 255) & ~(size_t)255;
        return p;
    };
    int* cnt       = (int*)alloc((size_t)2 * N * sizeof(int));  // cnt + fill contiguous
    int* fill      = cnt + N;
    int* row_ptr   = (int*)alloc((size_t)(N + 1) * sizeof(int));
    int2* ecol     = (int2*)alloc((size_t)E * sizeof(int2));
    float* dis     = (float*)alloc((size_t)N * sizeof(float));
    float* dinv    = (float*)alloc((size_t)N * sizeof(float));
    int* bsum      = (int*)alloc((size_t)256 * sizeof(int));
    ushort_t* hbA  = (ushort_t*)alloc((size_t)N * 64 * sizeof(ushort_t));
    ushort_t* hbB  = (ushort_t*)alloc((size_t)N * 64 * sizeof(ushort_t));

    const int nb = (N + SCAN_CHUNK - 1) / SCAN_CHUNK;  // 98
    const int n4 = (2 * N + 3) / 4;                    // int4s to zero

    zero_int4<<<(n4 + 255) / 256, 256, 0, stream>>>((int4*)cnt, n4);
    count_deg<<<(E + 255) / 256, 256, 0, stream>>>(dst, cnt, E);
    block_sum<<<nb, 256, 0, stream>>>(cnt, bsum, N);
    scan_bsums<<<1, 256, 0, stream>>>(bsum, nb, row_ptr, N);
    scan_final<<<nb, 256, 0, stream>>>(cnt, bsum, row_ptr, dis, dinv, N);
    fill_csr<<<(E + EPB - 1) / EPB, 256, 0, stream>>>(src, dst, row_ptr, fill, ecol, dis, E);

    // layer 1 GEMM: x (fp32) @ W1 -> hbA (bf16)
    gemm_lds<64, 16><<<(N + 15) / 16, 256, 0, stream>>>(x, W1, N, hbA);
    // fused agg1+gemm2, agg2+gemm3, agg3+gemm4
    agg_gemm<64><<<(N + 15) / 16, 256, 0, stream>>>(hbA, row_ptr, ecol, dinv, b1, W2, N, hbB);
    agg_gemm<64><<<(N + 15) / 16, 256, 0, stream>>>(hbB, row_ptr, ecol, dinv, b2, W3, N, hbA);
    agg_gemm<32><<<(N + 15) / 16, 256, 0, stream>>>(hbA, row_ptr, ecol, dinv, b3, W4, N, hbB);
    // final aggregation (F=32) -> d_out fp32
    agg_final<<<(N + 31) / 32, 256, 0, stream>>>(hbB, row_ptr, ecol, dinv, b4, (float*)d_out, N);
}

// Round 9
// 238.126 us; speedup vs baseline: 2.6857x; 1.0080x over previous
//
#include <hip/hip_runtime.h>

#define NN 100000
#define SCAN_CHUNK 1024

typedef unsigned short ushort_t;

__device__ inline ushort_t f2bf(float f) {
    unsigned int b = __float_as_uint(f);
    unsigned int r = (b + 0x7FFFu + ((b >> 16) & 1u)) >> 16;
    return (ushort_t)r;
}
__device__ inline float bf2f(ushort_t u) {
    return __int_as_float(((unsigned int)u) << 16);
}

// ---------------- zero workspace ints ----------------
__global__ __launch_bounds__(256) void zero_int4(int4* __restrict__ p, int n4) {
    int i = blockIdx.x * 256 + threadIdx.x;
    if (i < n4) p[i] = make_int4(0, 0, 0, 0);
}

// ---------------- degree count ----------------
__global__ __launch_bounds__(256) void count_deg(const int* __restrict__ dst,
                                                 int* __restrict__ cnt, int E) {
    int e = blockIdx.x * 256 + threadIdx.x;
    if (e < E) atomicAdd(&cnt[dst[e]], 1);
}

// ---------------- pass 1: per-block (1024-elem chunk) sums ----------------
__global__ __launch_bounds__(256) void block_sum(const int* __restrict__ cnt,
                                                 int* __restrict__ bsum, int N) {
    __shared__ int ws[4];
    const int tid = threadIdx.x, lane = tid & 63, wid = tid >> 6;
    int i0 = blockIdx.x * SCAN_CHUNK + tid * 4;
    int s = 0;
    if (i0 + 3 < N) {
        int4 v = *(const int4*)(cnt + i0);
        s = v.x + v.y + v.z + v.w;
    } else {
#pragma unroll
        for (int j = 0; j < 4; ++j) { int i = i0 + j; if (i < N) s += cnt[i]; }
    }
#pragma unroll
    for (int off = 32; off; off >>= 1) s += __shfl_down(s, off, 64);
    if (lane == 0) ws[wid] = s;
    __syncthreads();
    if (tid == 0) bsum[blockIdx.x] = ws[0] + ws[1] + ws[2] + ws[3];
}

// ---------------- pass 2: scan the block sums (nb <= 256), write total ----------------
__global__ __launch_bounds__(256) void scan_bsums(int* __restrict__ bsum, int nb,
                                                  int* __restrict__ row_ptr, int N) {
    __shared__ int ws[4];
    const int tid = threadIdx.x, lane = tid & 63, wid = tid >> 6;
    int v = (tid < nb) ? bsum[tid] : 0;
    int x = v;
#pragma unroll
    for (int off = 1; off < 64; off <<= 1) {
        int y = __shfl_up(x, off, 64);
        if (lane >= off) x += y;
    }
    if (lane == 63) ws[wid] = x;
    __syncthreads();
    int woff = 0;
    for (int w = 0; w < wid; ++w) woff += ws[w];
    int incl = x + woff;
    if (tid < nb) bsum[tid] = incl - v;        // exclusive block offset
    if (tid == nb - 1) row_ptr[N] = incl;      // grand total = E
}

// ---------------- pass 3: local exclusive scan + block offset + deg terms ----------------
__global__ __launch_bounds__(256) void scan_final(const int* __restrict__ cnt,
                                                  const int* __restrict__ bsum,
                                                  int* __restrict__ row_ptr,
                                                  float* __restrict__ dinv_sqrt, int N) {
    __shared__ int ws[4];
    const int tid = threadIdx.x, lane = tid & 63, wid = tid >> 6;
    int i0 = blockIdx.x * SCAN_CHUNK + tid * 4;
    int v[4];
    if (i0 + 3 < N) {
        int4 t = *(const int4*)(cnt + i0);
        v[0] = t.x; v[1] = t.y; v[2] = t.z; v[3] = t.w;
    } else {
#pragma unroll
        for (int j = 0; j < 4; ++j) { int i = i0 + j; v[j] = (i < N) ? cnt[i] : 0; }
    }
    int tsum = v[0] + v[1] + v[2] + v[3];
    int x = tsum;
#pragma unroll
    for (int off = 1; off < 64; off <<= 1) {
        int y = __shfl_up(x, off, 64);
        if (lane >= off) x += y;
    }
    if (lane == 63) ws[wid] = x;
    __syncthreads();
    int woff = 0;
    for (int w = 0; w < wid; ++w) woff += ws[w];
    int excl = bsum[blockIdx.x] + woff + (x - tsum);
#pragma unroll
    for (int j = 0; j < 4; ++j) {
        int i = i0 + j;
        if (i < N) {
            row_ptr[i] = excl;
            dinv_sqrt[i] = rsqrtf((float)v[j] + 1.0f);
        }
        excl += v[j];
    }
}

// ---------------- CSR fill: col only (4B per edge) ----------------
__global__ __launch_bounds__(256) void fill_csr(const int* __restrict__ src,
                                                const int* __restrict__ dst,
                                                const int* __restrict__ row_ptr,
                                                int* __restrict__ fill,
                                                int* __restrict__ col, int E) {
    int e = blockIdx.x * 256 + threadIdx.x;
    if (e >= E) return;
    int d = dst[e];
    int pos = row_ptr[d] + atomicAdd(&fill[d], 1);
    col[pos] = src[e];
}

// ---------------- unweighted edge sum: 4 features/lane (ushort4 gather) ----------------
// h' is pre-scaled by ds[src] in the producing GEMM, so no per-edge norm needed.
template <int F>
__device__ inline float4 agg_edges_v4(const ushort_t* __restrict__ h,
                                      const int* __restrict__ col,
                                      int e0, int e1, int fbase, float4 acc) {
    float4 accB = make_float4(0.f, 0.f, 0.f, 0.f);
    int e = e0;
    for (; e + 8 <= e1; e += 8) {
        int c[8];
#pragma unroll
        for (int j = 0; j < 8; ++j) c[j] = col[e + j];
        ushort4 u[8];
#pragma unroll
        for (int j = 0; j < 8; ++j) u[j] = *(const ushort4*)(h + (size_t)c[j] * F + fbase);
#pragma unroll
        for (int j = 0; j < 8; j += 2) {
            acc.x  += bf2f(u[j].x);     acc.y  += bf2f(u[j].y);
            acc.z  += bf2f(u[j].z);     acc.w  += bf2f(u[j].w);
            accB.x += bf2f(u[j + 1].x); accB.y += bf2f(u[j + 1].y);
            accB.z += bf2f(u[j + 1].z); accB.w += bf2f(u[j + 1].w);
        }
    }
    if (e + 4 <= e1) {
        int c[4];
#pragma unroll
        for (int j = 0; j < 4; ++j) c[j] = col[e + j];
        ushort4 u[4];
#pragma unroll
        for (int j = 0; j < 4; ++j) u[j] = *(const ushort4*)(h + (size_t)c[j] * F + fbase);
#pragma unroll
        for (int j = 0; j < 4; j += 2) {
            acc.x  += bf2f(u[j].x);     acc.y  += bf2f(u[j].y);
            acc.z  += bf2f(u[j].z);     acc.w  += bf2f(u[j].w);
            accB.x += bf2f(u[j + 1].x); accB.y += bf2f(u[j + 1].y);
            accB.z += bf2f(u[j + 1].z); accB.w += bf2f(u[j + 1].w);
        }
        e += 4;
    }
    for (; e < e1; ++e) {
        ushort4 u = *(const ushort4*)(h + (size_t)col[e] * F + fbase);
        acc.x += bf2f(u.x); acc.y += bf2f(u.y);
        acc.z += bf2f(u.z); acc.w += bf2f(u.w);
    }
    acc.x += accB.x; acc.y += accB.y; acc.z += accB.z; acc.w += accB.w;
    return acc;
}

// ---------------- dense GEMM h' = ds[row] * (in @ W), LDS-tiled, bf16 output ----------------
template <int FOUT, int R>
__global__ __launch_bounds__(256) void gemm_lds(const float* __restrict__ in,
                                                const float* __restrict__ W,
                                                const float* __restrict__ ds, int n,
                                                ushort_t* __restrict__ h) {
    constexpr int XS = 68;
    __shared__ float xs[R * XS];
    __shared__ float ws[64 * FOUT];
    const int tid = threadIdx.x;
    const int r0 = blockIdx.x * R;
    {
        const float4* xsrc = (const float4*)(in + (size_t)r0 * 64);
        constexpr int NF4 = R * 16;
#pragma unroll
        for (int i = tid; i < NF4; i += 256) {
            int row = i >> 4, kk = (i & 15) << 2;
            float4 v = make_float4(0.f, 0.f, 0.f, 0.f);
            if (r0 + row < n) v = xsrc[i];
            *(float4*)(xs + row * XS + kk) = v;
        }
        const float4* wsrc = (const float4*)W;
#pragma unroll
        for (int i = tid; i < 64 * FOUT / 4; i += 256)
            *(float4*)(ws + i * 4) = wsrc[i];
    }
    __syncthreads();
    constexpr int CG = FOUT / 4;
    const int row = tid / CG;
    const int col = (tid % CG) * 4;
    float4 acc = make_float4(0.f, 0.f, 0.f, 0.f);
#pragma unroll
    for (int k = 0; k < 64; k += 4) {
        float4 xv = *(const float4*)(xs + row * XS + k);
#pragma unroll
        for (int kk = 0; kk < 4; ++kk) {
            float a = (&xv.x)[kk];
            float4 wv = *(const float4*)(ws + (k + kk) * FOUT + col);
            acc.x = fmaf(a, wv.x, acc.x);
            acc.y = fmaf(a, wv.y, acc.y);
            acc.z = fmaf(a, wv.z, acc.z);
            acc.w = fmaf(a, wv.w, acc.w);
        }
    }
    int orow = r0 + row;
    if (orow < n) {
        float dsv = ds[orow];
        ushort4 o;
        o.x = f2bf(acc.x * dsv); o.y = f2bf(acc.y * dsv);
        o.z = f2bf(acc.z * dsv); o.w = f2bf(acc.w * dsv);
        *(ushort4*)(h + (size_t)orow * FOUT + col) = o;
    }
}

// ---------------- FUSED: agg(F_IN=64, relu) -> LDS -> gemm(next layer, ds-scaled out) ----------------
// agg phase: 16 lanes per row (4 features/lane), 4 rows per wave concurrently.
template <int FOUT>
__global__ __launch_bounds__(256) void agg_gemm(const ushort_t* __restrict__ hin,
                                                const int* __restrict__ row_ptr,
                                                const int* __restrict__ col,
                                                const float* __restrict__ ds,
                                                const float* __restrict__ bagg,
                                                const float* __restrict__ W, int n,
                                                ushort_t* __restrict__ hout) {
    constexpr int R = 16;
    constexpr int XS = 68;
    __shared__ float xs[R * XS];
    __shared__ float ws[64 * FOUT];
    const int tid = threadIdx.x, lane = tid & 63, wid = tid >> 6;
    const int r0 = blockIdx.x * R;
    // stage W
    const float4* wsrc = (const float4*)W;
#pragma unroll
    for (int i = tid; i < 64 * FOUT / 4; i += 256)
        *(float4*)(ws + i * 4) = wsrc[i];
    // phase A: aggregate (4 rows per wave in parallel)
    {
        const int sub = lane >> 4;         // row within wave's quad
        const int fbase = (lane & 15) * 4; // feature slice
        const int row = wid * 4 + sub;
        const int g = r0 + row;
        if (g < n) {
            ushort4 us = *(const ushort4*)(hin + (size_t)g * 64 + fbase);
            float4 acc;
            acc.x = bf2f(us.x); acc.y = bf2f(us.y);
            acc.z = bf2f(us.z); acc.w = bf2f(us.w);
            acc = agg_edges_v4<64>(hin, col, row_ptr[g], row_ptr[g + 1], fbase, acc);
            float dsv = ds[g];
            float4 r;
            r.x = fmaxf(fmaf(acc.x, dsv, bagg[fbase + 0]), 0.f);
            r.y = fmaxf(fmaf(acc.y, dsv, bagg[fbase + 1]), 0.f);
            r.z = fmaxf(fmaf(acc.z, dsv, bagg[fbase + 2]), 0.f);
            r.w = fmaxf(fmaf(acc.w, dsv, bagg[fbase + 3]), 0.f);
            *(float4*)(xs + row * XS + fbase) = r;
        }
    }
    __syncthreads();
    // phase B: gemm from xs (only rows < R are valid/needed)
    constexpr int CG = FOUT / 4;
    const int row = tid / CG;
    const int cg = (tid % CG) * 4;
    if (row < R) {
        float4 acc = make_float4(0.f, 0.f, 0.f, 0.f);
#pragma unroll
        for (int k = 0; k < 64; k += 4) {
            float4 xv = *(const float4*)(xs + row * XS + k);
#pragma unroll
            for (int kk = 0; kk < 4; ++kk) {
                float a = (&xv.x)[kk];
                float4 wv = *(const float4*)(ws + (k + kk) * FOUT + cg);
                acc.x = fmaf(a, wv.x, acc.x);
                acc.y = fmaf(a, wv.y, acc.y);
                acc.z = fmaf(a, wv.z, acc.z);
                acc.w = fmaf(a, wv.w, acc.w);
            }
        }
        int orow = r0 + row;
        if (orow < n) {
            float dsv = ds[orow];
            ushort4 o;
            o.x = f2bf(acc.x * dsv); o.y = f2bf(acc.y * dsv);
            o.z = f2bf(acc.z * dsv); o.w = f2bf(acc.w * dsv);
            *(ushort4*)(hout + (size_t)orow * FOUT + cg) = o;
        }
    }
}

// ---------------- final aggregation (F=32, fp32 out): 8 lanes/row, 8 rows/wave ----------------
__global__ __launch_bounds__(256) void agg_final(const ushort_t* __restrict__ h,
                                                 const int* __restrict__ row_ptr,
                                                 const int* __restrict__ col,
                                                 const float* __restrict__ ds,
                                                 const float* __restrict__ b,
                                                 float* __restrict__ out, int n) {
    const int tid = threadIdx.x, lane = tid & 63, wid = tid >> 6;
    const int sub = lane >> 3;         // 0..7
    const int fbase = (lane & 7) * 4;
    int g = blockIdx.x * 32 + wid * 8 + sub;
    if (g >= n) return;
    ushort4 us = *(const ushort4*)(h + (size_t)g * 32 + fbase);
    float4 acc;
    acc.x = bf2f(us.x); acc.y = bf2f(us.y);
    acc.z = bf2f(us.z); acc.w = bf2f(us.w);
    acc = agg_edges_v4<32>(h, col, row_ptr[g], row_ptr[g + 1], fbase, acc);
    float dsv = ds[g];
    float4 o;
    o.x = fmaf(acc.x, dsv, b[fbase + 0]);
    o.y = fmaf(acc.y, dsv, b[fbase + 1]);
    o.z = fmaf(acc.z, dsv, b[fbase + 2]);
    o.w = fmaf(acc.w, dsv, b[fbase + 3]);
    *(float4*)(out + (size_t)g * 32 + fbase) = o;
}

extern "C" void kernel_launch(void* const* d_in, const int* in_sizes, int n_in,
                              void* d_out, int out_size, void* d_ws, size_t ws_size,
                              hipStream_t stream) {
    const float* x  = (const float*)d_in[0];
    const int* edge = (const int*)d_in[1];
    const float* W1 = (const float*)d_in[2];
    const float* b1 = (const float*)d_in[3];
    const float* W2 = (const float*)d_in[4];
    const float* b2 = (const float*)d_in[5];
    const float* W3 = (const float*)d_in[6];
    const float* b3 = (const float*)d_in[7];
    const float* W4 = (const float*)d_in[8];
    const float* b4 = (const float*)d_in[9];

    const int N = NN;
    const int E = in_sizes[1] / 2;
    const int* src = edge;
    const int* dst = edge + E;

    char* ws = (char*)d_ws;
    size_t off = 0;
    auto alloc = [&](size_t bytes) -> void* {
        void* p = ws + off;
        off += (bytes + 255) & ~(size_t)255;
        return p;
    };
    int* cnt       = (int*)alloc((size_t)2 * N * sizeof(int));  // cnt + fill contiguous
    int* fill      = cnt + N;
    int* row_ptr   = (int*)alloc((size_t)(N + 1) * sizeof(int));
    int* col       = (int*)alloc((size_t)E * sizeof(int));
    float* dis     = (float*)alloc((size_t)N * sizeof(float));
    int* bsum      = (int*)alloc((size_t)256 * sizeof(int));
    ushort_t* hbA  = (ushort_t*)alloc((size_t)N * 64 * sizeof(ushort_t));
    ushort_t* hbB  = (ushort_t*)alloc((size_t)N * 64 * sizeof(ushort_t));

    const int nb = (N + SCAN_CHUNK - 1) / SCAN_CHUNK;  // 98
    const int n4 = (2 * N + 3) / 4;                    // int4s to zero

    zero_int4<<<(n4 + 255) / 256, 256, 0, stream>>>((int4*)cnt, n4);
    count_deg<<<(E + 255) / 256, 256, 0, stream>>>(dst, cnt, E);
    block_sum<<<nb, 256, 0, stream>>>(cnt, bsum, N);
    scan_bsums<<<1, 256, 0, stream>>>(bsum, nb, row_ptr, N);
    scan_final<<<nb, 256, 0, stream>>>(cnt, bsum, row_ptr, dis, N);
    fill_csr<<<(E + 255) / 256, 256, 0, stream>>>(src, dst, row_ptr, fill, col, E);

    // layer 1 GEMM: x (fp32) @ W1, ds-scaled -> hbA (bf16)
    gemm_lds<64, 16><<<(N + 15) / 16, 256, 0, stream>>>(x, W1, dis, N, hbA);
    // fused agg1+gemm2, agg2+gemm3, agg3+gemm4 (all ds-scaled bf16 out)
    agg_gemm<64><<<(N + 15) / 16, 256, 0, stream>>>(hbA, row_ptr, col, dis, b1, W2, N, hbB);
    agg_gemm<64><<<(N + 15) / 16, 256, 0, stream>>>(hbB, row_ptr, col, dis, b2, W3, N, hbA);
    agg_gemm<32><<<(N + 15) / 16, 256, 0, stream>>>(hbA, row_ptr, col, dis, b3, W4, N, hbB);
    // final aggregation (F=32) -> d_out fp32
    agg_final<<<(N + 31) / 32, 256, 0, stream>>>(hbB, row_ptr, col, dis, b4, (float*)d_out, N);
}

// Round 10
// 212.430 us; speedup vs baseline: 3.0106x; 1.1210x over previous
//
#include <hip/hip_runtime.h>

#define NN 100000
#define SCAN_CHUNK 1024
#define BSHIFT 8
#define NB 391      // ceil(NN / 256)
#define EPA 4096    // edges per part_a block

typedef unsigned short ushort_t;

__device__ inline ushort_t f2bf(float f) {
    unsigned int b = __float_as_uint(f);
    unsigned int r = (b + 0x7FFFu + ((b >> 16) & 1u)) >> 16;
    return (ushort_t)r;
}
__device__ inline float bf2f(ushort_t u) {
    return __int_as_float(((unsigned int)u) << 16);
}

// ---------------- zero workspace ints ----------------
__global__ __launch_bounds__(256) void zero_int4(int4* __restrict__ p, int n4) {
    int i = blockIdx.x * 256 + threadIdx.x;
    if (i < n4) p[i] = make_int4(0, 0, 0, 0);
}

// ---------------- degree count ----------------
__global__ __launch_bounds__(256) void count_deg(const int* __restrict__ dst,
                                                 int* __restrict__ cnt, int E) {
    int e = blockIdx.x * 256 + threadIdx.x;
    if (e < E) atomicAdd(&cnt[dst[e]], 1);
}

// ---------------- pass 1: per-block (1024-elem chunk) sums ----------------
__global__ __launch_bounds__(256) void block_sum(const int* __restrict__ cnt,
                                                 int* __restrict__ bsum, int N) {
    __shared__ int ws[4];
    const int tid = threadIdx.x, lane = tid & 63, wid = tid >> 6;
    int i0 = blockIdx.x * SCAN_CHUNK + tid * 4;
    int s = 0;
    if (i0 + 3 < N) {
        int4 v = *(const int4*)(cnt + i0);
        s = v.x + v.y + v.z + v.w;
    } else {
#pragma unroll
        for (int j = 0; j < 4; ++j) { int i = i0 + j; if (i < N) s += cnt[i]; }
    }
#pragma unroll
    for (int off = 32; off; off >>= 1) s += __shfl_down(s, off, 64);
    if (lane == 0) ws[wid] = s;
    __syncthreads();
    if (tid == 0) bsum[blockIdx.x] = ws[0] + ws[1] + ws[2] + ws[3];
}

// ---------------- pass 2: scan the block sums (nb <= 256), write total ----------------
__global__ __launch_bounds__(256) void scan_bsums(int* __restrict__ bsum, int nb,
                                                  int* __restrict__ row_ptr, int N) {
    __shared__ int ws[4];
    const int tid = threadIdx.x, lane = tid & 63, wid = tid >> 6;
    int v = (tid < nb) ? bsum[tid] : 0;
    int x = v;
#pragma unroll
    for (int off = 1; off < 64; off <<= 1) {
        int y = __shfl_up(x, off, 64);
        if (lane >= off) x += y;
    }
    if (lane == 63) ws[wid] = x;
    __syncthreads();
    int woff = 0;
    for (int w = 0; w < wid; ++w) woff += ws[w];
    int incl = x + woff;
    if (tid < nb) bsum[tid] = incl - v;        // exclusive block offset
    if (tid == nb - 1) row_ptr[N] = incl;      // grand total = E
}

// ---------------- pass 3: local exclusive scan + block offset + deg terms ----------------
__global__ __launch_bounds__(256) void scan_final(const int* __restrict__ cnt,
                                                  const int* __restrict__ bsum,
                                                  int* __restrict__ row_ptr,
                                                  float* __restrict__ dinv_sqrt, int N) {
    __shared__ int ws[4];
    const int tid = threadIdx.x, lane = tid & 63, wid = tid >> 6;
    int i0 = blockIdx.x * SCAN_CHUNK + tid * 4;
    int v[4];
    if (i0 + 3 < N) {
        int4 t = *(const int4*)(cnt + i0);
        v[0] = t.x; v[1] = t.y; v[2] = t.z; v[3] = t.w;
    } else {
#pragma unroll
        for (int j = 0; j < 4; ++j) { int i = i0 + j; v[j] = (i < N) ? cnt[i] : 0; }
    }
    int tsum = v[0] + v[1] + v[2] + v[3];
    int x = tsum;
#pragma unroll
    for (int off = 1; off < 64; off <<= 1) {
        int y = __shfl_up(x, off, 64);
        if (lane >= off) x += y;
    }
    if (lane == 63) ws[wid] = x;
    __syncthreads();
    int woff = 0;
    for (int w = 0; w < wid; ++w) woff += ws[w];
    int excl = bsum[blockIdx.x] + woff + (x - tsum);
#pragma unroll
    for (int j = 0; j < 4; ++j) {
        int i = i0 + j;
        if (i < N) {
            row_ptr[i] = excl;
            dinv_sqrt[i] = rsqrtf((float)v[j] + 1.0f);
        }
        excl += v[j];
    }
}

// ---------------- part A: multisplit into 391 dst-buckets (256 nodes each) ----------------
// Stage packed (src | dloc<<17) into the bucket's exact CSR-aligned region.
__global__ __launch_bounds__(256) void part_a(const int* __restrict__ src,
                                              const int* __restrict__ dst,
                                              const int* __restrict__ row_ptr,
                                              int* __restrict__ gfill,
                                              int* __restrict__ stage, int E) {
    __shared__ int hist[NB];
    __shared__ int base[NB];
    const int tid = threadIdx.x;
    const int e0 = blockIdx.x * EPA;
    for (int i = tid; i < NB; i += 256) hist[i] = 0;
    __syncthreads();
    int es[16], eb[16];
#pragma unroll
    for (int k = 0; k < 16; ++k) {
        int e = e0 + k * 256 + tid;
        if (e < E) {
            int d = dst[e];
            eb[k] = d >> BSHIFT;
            es[k] = src[e] | ((d & 255) << 17);
            atomicAdd(&hist[eb[k]], 1);
        } else {
            eb[k] = -1;
        }
    }
    __syncthreads();
    for (int i = tid; i < NB; i += 256) {
        int c = hist[i];
        int g = (c > 0) ? atomicAdd(&gfill[i], c) : 0;
        base[i] = row_ptr[i << BSHIFT] + g;
        hist[i] = 0;   // reuse as running offset
    }
    __syncthreads();
#pragma unroll
    for (int k = 0; k < 16; ++k) {
        if (eb[k] >= 0) {
            int idx = atomicAdd(&hist[eb[k]], 1);
            stage[base[eb[k]] + idx] = es[k];
        }
    }
}

// ---------------- part B: exact placement within bucket (one block owns one bucket) ----------------
__global__ __launch_bounds__(256) void part_b(const int* __restrict__ row_ptr,
                                              const int* __restrict__ stage,
                                              int* __restrict__ col, int N) {
    __shared__ int rp[257];
    __shared__ int lfill[256];
    const int tid = threadIdx.x;
    const int lo = blockIdx.x << BSHIFT;
    const int nn = min(256, N - lo);
    for (int i = tid; i <= nn; i += 256) rp[i] = row_ptr[lo + i];
    lfill[tid] = 0;
    __syncthreads();
    const int ebase = rp[0], eend = rp[nn];
    for (int e = ebase + tid; e < eend; e += 256) {
        int v = stage[e];
        int dloc = (v >> 17) & 255;
        int pos = rp[dloc] + atomicAdd(&lfill[dloc], 1);
        col[pos] = v & 0x1FFFF;
    }
}

// ---------------- unweighted edge sum: 4 features/lane (ushort4 gather) ----------------
template <int F>
__device__ inline float4 agg_edges_v4(const ushort_t* __restrict__ h,
                                      const int* __restrict__ col,
                                      int e0, int e1, int fbase, float4 acc) {
    float4 accB = make_float4(0.f, 0.f, 0.f, 0.f);
    int e = e0;
    for (; e + 8 <= e1; e += 8) {
        int c[8];
#pragma unroll
        for (int j = 0; j < 8; ++j) c[j] = col[e + j];
        ushort4 u[8];
#pragma unroll
        for (int j = 0; j < 8; ++j) u[j] = *(const ushort4*)(h + (size_t)c[j] * F + fbase);
#pragma unroll
        for (int j = 0; j < 8; j += 2) {
            acc.x  += bf2f(u[j].x);     acc.y  += bf2f(u[j].y);
            acc.z  += bf2f(u[j].z);     acc.w  += bf2f(u[j].w);
            accB.x += bf2f(u[j + 1].x); accB.y += bf2f(u[j + 1].y);
            accB.z += bf2f(u[j + 1].z); accB.w += bf2f(u[j + 1].w);
        }
    }
    if (e + 4 <= e1) {
        int c[4];
#pragma unroll
        for (int j = 0; j < 4; ++j) c[j] = col[e + j];
        ushort4 u[4];
#pragma unroll
        for (int j = 0; j < 4; ++j) u[j] = *(const ushort4*)(h + (size_t)c[j] * F + fbase);
#pragma unroll
        for (int j = 0; j < 4; j += 2) {
            acc.x  += bf2f(u[j].x);     acc.y  += bf2f(u[j].y);
            acc.z  += bf2f(u[j].z);     acc.w  += bf2f(u[j].w);
            accB.x += bf2f(u[j + 1].x); accB.y += bf2f(u[j + 1].y);
            accB.z += bf2f(u[j + 1].z); accB.w += bf2f(u[j + 1].w);
        }
        e += 4;
    }
    for (; e < e1; ++e) {
        ushort4 u = *(const ushort4*)(h + (size_t)col[e] * F + fbase);
        acc.x += bf2f(u.x); acc.y += bf2f(u.y);
        acc.z += bf2f(u.z); acc.w += bf2f(u.w);
    }
    acc.x += accB.x; acc.y += accB.y; acc.z += accB.z; acc.w += accB.w;
    return acc;
}

// ---------------- dense GEMM h' = ds[row] * (in @ W), LDS-tiled, bf16 output ----------------
template <int FOUT, int R>
__global__ __launch_bounds__(256) void gemm_lds(const float* __restrict__ in,
                                                const float* __restrict__ W,
                                                const float* __restrict__ ds, int n,
                                                ushort_t* __restrict__ h) {
    constexpr int XS = 68;
    __shared__ float xs[R * XS];
    __shared__ float ws[64 * FOUT];
    const int tid = threadIdx.x;
    const int r0 = blockIdx.x * R;
    {
        const float4* xsrc = (const float4*)(in + (size_t)r0 * 64);
        constexpr int NF4 = R * 16;
#pragma unroll
        for (int i = tid; i < NF4; i += 256) {
            int row = i >> 4, kk = (i & 15) << 2;
            float4 v = make_float4(0.f, 0.f, 0.f, 0.f);
            if (r0 + row < n) v = xsrc[i];
            *(float4*)(xs + row * XS + kk) = v;
        }
        const float4* wsrc = (const float4*)W;
#pragma unroll
        for (int i = tid; i < 64 * FOUT / 4; i += 256)
            *(float4*)(ws + i * 4) = wsrc[i];
    }
    __syncthreads();
    constexpr int CG = FOUT / 4;
    const int row = tid / CG;
    const int col = (tid % CG) * 4;
    float4 acc = make_float4(0.f, 0.f, 0.f, 0.f);
#pragma unroll
    for (int k = 0; k < 64; k += 4) {
        float4 xv = *(const float4*)(xs + row * XS + k);
#pragma unroll
        for (int kk = 0; kk < 4; ++kk) {
            float a = (&xv.x)[kk];
            float4 wv = *(const float4*)(ws + (k + kk) * FOUT + col);
            acc.x = fmaf(a, wv.x, acc.x);
            acc.y = fmaf(a, wv.y, acc.y);
            acc.z = fmaf(a, wv.z, acc.z);
            acc.w = fmaf(a, wv.w, acc.w);
        }
    }
    int orow = r0 + row;
    if (orow < n) {
        float dsv = ds[orow];
        ushort4 o;
        o.x = f2bf(acc.x * dsv); o.y = f2bf(acc.y * dsv);
        o.z = f2bf(acc.z * dsv); o.w = f2bf(acc.w * dsv);
        *(ushort4*)(h + (size_t)orow * FOUT + col) = o;
    }
}

// ---------------- FUSED: agg(F_IN=64, relu) -> LDS -> gemm(next layer, ds-scaled out) ----------------
template <int FOUT>
__global__ __launch_bounds__(256) void agg_gemm(const ushort_t* __restrict__ hin,
                                                const int* __restrict__ row_ptr,
                                                const int* __restrict__ col,
                                                const float* __restrict__ ds,
                                                const float* __restrict__ bagg,
                                                const float* __restrict__ W, int n,
                                                ushort_t* __restrict__ hout) {
    constexpr int R = 16;
    constexpr int XS = 68;
    __shared__ float xs[R * XS];
    __shared__ float ws[64 * FOUT];
    const int tid = threadIdx.x, lane = tid & 63, wid = tid >> 6;
    const int r0 = blockIdx.x * R;
    // stage W
    const float4* wsrc = (const float4*)W;
#pragma unroll
    for (int i = tid; i < 64 * FOUT / 4; i += 256)
        *(float4*)(ws + i * 4) = wsrc[i];
    // phase A: aggregate (4 rows per wave in parallel)
    {
        const int sub = lane >> 4;         // row within wave's quad
        const int fbase = (lane & 15) * 4; // feature slice
        const int row = wid * 4 + sub;
        const int g = r0 + row;
        if (g < n) {
            ushort4 us = *(const ushort4*)(hin + (size_t)g * 64 + fbase);
            float4 acc;
            acc.x = bf2f(us.x); acc.y = bf2f(us.y);
            acc.z = bf2f(us.z); acc.w = bf2f(us.w);
            acc = agg_edges_v4<64>(hin, col, row_ptr[g], row_ptr[g + 1], fbase, acc);
            float dsv = ds[g];
            float4 r;
            r.x = fmaxf(fmaf(acc.x, dsv, bagg[fbase + 0]), 0.f);
            r.y = fmaxf(fmaf(acc.y, dsv, bagg[fbase + 1]), 0.f);
            r.z = fmaxf(fmaf(acc.z, dsv, bagg[fbase + 2]), 0.f);
            r.w = fmaxf(fmaf(acc.w, dsv, bagg[fbase + 3]), 0.f);
            *(float4*)(xs + row * XS + fbase) = r;
        }
    }
    __syncthreads();
    // phase B: gemm from xs (only rows < R are valid/needed)
    constexpr int CG = FOUT / 4;
    const int row = tid / CG;
    const int cg = (tid % CG) * 4;
    if (row < R) {
        float4 acc = make_float4(0.f, 0.f, 0.f, 0.f);
#pragma unroll
        for (int k = 0; k < 64; k += 4) {
            float4 xv = *(const float4*)(xs + row * XS + k);
#pragma unroll
            for (int kk = 0; kk < 4; ++kk) {
                float a = (&xv.x)[kk];
                float4 wv = *(const float4*)(ws + (k + kk) * FOUT + cg);
                acc.x = fmaf(a, wv.x, acc.x);
                acc.y = fmaf(a, wv.y, acc.y);
                acc.z = fmaf(a, wv.z, acc.z);
                acc.w = fmaf(a, wv.w, acc.w);
            }
        }
        int orow = r0 + row;
        if (orow < n) {
            float dsv = ds[orow];
            ushort4 o;
            o.x = f2bf(acc.x * dsv); o.y = f2bf(acc.y * dsv);
            o.z = f2bf(acc.z * dsv); o.w = f2bf(acc.w * dsv);
            *(ushort4*)(hout + (size_t)orow * FOUT + cg) = o;
        }
    }
}

// ---------------- final aggregation (F=32, fp32 out): 8 lanes/row, 8 rows/wave ----------------
__global__ __launch_bounds__(256) void agg_final(const ushort_t* __restrict__ h,
                                                 const int* __restrict__ row_ptr,
                                                 const int* __restrict__ col,
                                                 const float* __restrict__ ds,
                                                 const float* __restrict__ b,
                                                 float* __restrict__ out, int n) {
    const int tid = threadIdx.x, lane = tid & 63, wid = tid >> 6;
    const int sub = lane >> 3;         // 0..7
    const int fbase = (lane & 7) * 4;
    int g = blockIdx.x * 32 + wid * 8 + sub;
    if (g >= n) return;
    ushort4 us = *(const ushort4*)(h + (size_t)g * 32 + fbase);
    float4 acc;
    acc.x = bf2f(us.x); acc.y = bf2f(us.y);
    acc.z = bf2f(us.z); acc.w = bf2f(us.w);
    acc = agg_edges_v4<32>(h, col, row_ptr[g], row_ptr[g + 1], fbase, acc);
    float dsv = ds[g];
    float4 o;
    o.x = fmaf(acc.x, dsv, b[fbase + 0]);
    o.y = fmaf(acc.y, dsv, b[fbase + 1]);
    o.z = fmaf(acc.z, dsv, b[fbase + 2]);
    o.w = fmaf(acc.w, dsv, b[fbase + 3]);
    *(float4*)(out + (size_t)g * 32 + fbase) = o;
}

extern "C" void kernel_launch(void* const* d_in, const int* in_sizes, int n_in,
                              void* d_out, int out_size, void* d_ws, size_t ws_size,
                              hipStream_t stream) {
    const float* x  = (const float*)d_in[0];
    const int* edge = (const int*)d_in[1];
    const float* W1 = (const float*)d_in[2];
    const float* b1 = (const float*)d_in[3];
    const float* W2 = (const float*)d_in[4];
    const float* b2 = (const float*)d_in[5];
    const float* W3 = (const float*)d_in[6];
    const float* b3 = (const float*)d_in[7];
    const float* W4 = (const float*)d_in[8];
    const float* b4 = (const float*)d_in[9];

    const int N = NN;
    const int E = in_sizes[1] / 2;
    const int* src = edge;
    const int* dst = edge + E;

    char* ws = (char*)d_ws;
    size_t off = 0;
    auto alloc = [&](size_t bytes) -> void* {
        void* p = ws + off;
        off += (bytes + 255) & ~(size_t)255;
        return p;
    };
    int* cnt       = (int*)alloc((size_t)(N + NB + 8) * sizeof(int));  // cnt + gfill contiguous
    int* gfill     = cnt + N;
    int* row_ptr   = (int*)alloc((size_t)(N + 1) * sizeof(int));
    int* col       = (int*)alloc((size_t)E * sizeof(int));
    int* stage     = (int*)alloc((size_t)E * sizeof(int));
    float* dis     = (float*)alloc((size_t)N * sizeof(float));
    int* bsum      = (int*)alloc((size_t)256 * sizeof(int));
    ushort_t* hbA  = (ushort_t*)alloc((size_t)N * 64 * sizeof(ushort_t));
    ushort_t* hbB  = (ushort_t*)alloc((size_t)N * 64 * sizeof(ushort_t));

    const int nb = (N + SCAN_CHUNK - 1) / SCAN_CHUNK;  // 98
    const int n4 = (N + NB + 8 + 3) / 4;               // int4s to zero (cnt+gfill)

    zero_int4<<<(n4 + 255) / 256, 256, 0, stream>>>((int4*)cnt, n4);
    count_deg<<<(E + 255) / 256, 256, 0, stream>>>(dst, cnt, E);
    block_sum<<<nb, 256, 0, stream>>>(cnt, bsum, N);
    scan_bsums<<<1, 256, 0, stream>>>(bsum, nb, row_ptr, N);
    scan_final<<<nb, 256, 0, stream>>>(cnt, bsum, row_ptr, dis, N);
    part_a<<<(E + EPA - 1) / EPA, 256, 0, stream>>>(src, dst, row_ptr, gfill, stage, E);
    part_b<<<NB, 256, 0, stream>>>(row_ptr, stage, col, N);

    // layer 1 GEMM: x (fp32) @ W1, ds-scaled -> hbA (bf16)
    gemm_lds<64, 16><<<(N + 15) / 16, 256, 0, stream>>>(x, W1, dis, N, hbA);
    // fused agg1+gemm2, agg2+gemm3, agg3+gemm4 (all ds-scaled bf16 out)
    agg_gemm<64><<<(N + 15) / 16, 256, 0, stream>>>(hbA, row_ptr, col, dis, b1, W2, N, hbB);
    agg_gemm<64><<<(N + 15) / 16, 256, 0, stream>>>(hbB, row_ptr, col, dis, b2, W3, N, hbA);
    agg_gemm<32><<<(N + 15) / 16, 256, 0, stream>>>(hbA, row_ptr, col, dis, b3, W4, N, hbB);
    // final aggregation (F=32) -> d_out fp32
    agg_final<<<(N + 31) / 32, 256, 0, stream>>>(hbB, row_ptr, col, dis, b4, (float*)d_out, N);
}